// Round 1
// baseline (605.332 us; speedup 1.0000x reference)
//
#include <hip/hip_runtime.h>

#define BB 4
#define NN 8192
#define DIM 128
#define NH 8
#define DH 64

// ---------------------------------------------------------------------------
// Kernel 1: for each (b, h, chunk of 512 rows):
//   kv = x_rows @ W_{k,v}  (128 cols: 0..63 = k, 64..127 = v), K = 128
//   InstanceNorm over each 64-wide segment (k and v separately, biased var)
//   dots[b,h] += k^T v   (accumulated in registers, atomicAdd at end)
// ---------------------------------------------------------------------------
__global__ __launch_bounds__(256) void kv_dots_kernel(const float* __restrict__ x,
                                                      const float* __restrict__ wqkv,
                                                      float* __restrict__ dots) {
  __shared__ __align__(16) float xs[64 * 32];    // XOR-swizzled [r][kk]
  __shared__ __align__(16) float ws[128 * 36];   // W^T [col][kk], pad 36
  __shared__ __align__(16) float kvs[64 * 132];  // kv tile [r][col], pad 132

  const int t = threadIdx.x;
  const int bx = blockIdx.x;
  const int chunk = bx & 15;
  const int h = (bx >> 4) & 7;
  const int b = bx >> 7;
  const int row0 = chunk * 512;

  const int rg = t >> 4;  // 0..15, rows rg+16i
  const int cg = t & 15;  // 0..15, cols cg+16j

  // staging assignment for xs
  const int sr = t >> 2;        // 0..63
  const int skb = (t & 3) * 8;  // kk base 0,8,16,24
  const int xsw = (sr & 7) << 2;

  // outer-product ownership: d = dg*2 + {0,1}, e = eg*8 + {0..7}
  const int dg = t >> 3;  // 0..31
  const int eg = t & 7;   // 0..7

  float dacc[2][8];
#pragma unroll
  for (int p = 0; p < 2; ++p)
#pragma unroll
    for (int q = 0; q < 8; ++q) dacc[p][q] = 0.f;

  for (int tile = 0; tile < 8; ++tile) {
    const int rowbase = row0 + tile * 64;
    float acc[4][8];
#pragma unroll
    for (int i = 0; i < 4; ++i)
#pragma unroll
      for (int j = 0; j < 8; ++j) acc[i][j] = 0.f;

    for (int ks = 0; ks < 4; ++ks) {
      // stage x tile (64 rows x 32 k-slice), XOR-swizzled for conflict-free reads
      {
        const float* gp = x + (size_t)(b * NN + rowbase + sr) * DIM + ks * 32 + skb;
        const float4 v0 = *(const float4*)gp;
        const float4 v1 = *(const float4*)(gp + 4);
        *(float4*)&xs[sr * 32 + (skb ^ xsw)] = v0;
        *(float4*)&xs[sr * 32 + ((skb + 4) ^ xsw)] = v1;
      }
      // stage W^T tile: ws[c][kk] = wqkv[ks*32+kk][colmap(c)]
#pragma unroll
      for (int m = 0; m < 16; ++m) {
        const int idx = t + 256 * m;
        const int c = idx & 127;
        const int kk = idx >> 7;  // 0..31
        const int ocol = (c < 64) ? (512 + h * 64 + c) : (1024 + h * 64 + (c - 64));
        ws[c * 36 + kk] = wqkv[(size_t)(ks * 32 + kk) * 1536 + ocol];
      }
      __syncthreads();

#pragma unroll
      for (int kk = 0; kk < 32; kk += 4) {
        float4 a[4];
#pragma unroll
        for (int i = 0; i < 4; ++i) {
          const int r = rg + 16 * i;
          a[i] = *(const float4*)&xs[r * 32 + (kk ^ ((r & 7) << 2))];
        }
#pragma unroll
        for (int j = 0; j < 8; ++j) {
          const float4 bv = *(const float4*)&ws[(cg + 16 * j) * 36 + kk];
#pragma unroll
          for (int i = 0; i < 4; ++i) {
            acc[i][j] += a[i].x * bv.x + a[i].y * bv.y + a[i].z * bv.z + a[i].w * bv.w;
          }
        }
      }
      __syncthreads();
    }

    // write kv tile to LDS
#pragma unroll
    for (int i = 0; i < 4; ++i) {
      const int r = rg + 16 * i;
#pragma unroll
      for (int j = 0; j < 8; ++j) kvs[r * 132 + cg + 16 * j] = acc[i][j];
    }
    __syncthreads();

    // InstanceNorm: seg = (row, half); 2 threads per seg, 32 elems each
    {
      const int row = t >> 2;
      const int half = (t >> 1) & 1;
      const int sub = t & 1;
      float* base = &kvs[row * 132 + half * 64 + sub * 32];
      float vreg[32];
      float s1 = 0.f, s2 = 0.f;
#pragma unroll
      for (int q = 0; q < 32; q += 4) {
        const float4 vv = *(const float4*)(base + q);
        vreg[q] = vv.x; vreg[q + 1] = vv.y; vreg[q + 2] = vv.z; vreg[q + 3] = vv.w;
        s1 += vv.x + vv.y + vv.z + vv.w;
        s2 += vv.x * vv.x + vv.y * vv.y + vv.z * vv.z + vv.w * vv.w;
      }
      s1 += __shfl_xor(s1, 1);
      s2 += __shfl_xor(s2, 1);
      const float mean = s1 * (1.f / 64.f);
      const float var = s2 * (1.f / 64.f) - mean * mean;
      const float sc = rsqrtf(var + 1e-5f);
#pragma unroll
      for (int q = 0; q < 32; q += 4) {
        float4 vv;
        vv.x = (vreg[q] - mean) * sc;
        vv.y = (vreg[q + 1] - mean) * sc;
        vv.z = (vreg[q + 2] - mean) * sc;
        vv.w = (vreg[q + 3] - mean) * sc;
        *(float4*)(base + q) = vv;
      }
    }
    __syncthreads();

    // outer-product accumulate: dots[d][e] += sum_r k[r][d] * v[r][e]
#pragma unroll 4
    for (int r = 0; r < 64; ++r) {
      const float k0 = kvs[r * 132 + dg * 2];
      const float k1 = kvs[r * 132 + dg * 2 + 1];
      const float4 v0 = *(const float4*)&kvs[r * 132 + 64 + eg * 8];
      const float4 v1 = *(const float4*)&kvs[r * 132 + 64 + eg * 8 + 4];
      dacc[0][0] += k0 * v0.x; dacc[0][1] += k0 * v0.y;
      dacc[0][2] += k0 * v0.z; dacc[0][3] += k0 * v0.w;
      dacc[0][4] += k0 * v1.x; dacc[0][5] += k0 * v1.y;
      dacc[0][6] += k0 * v1.z; dacc[0][7] += k0 * v1.w;
      dacc[1][0] += k1 * v0.x; dacc[1][1] += k1 * v0.y;
      dacc[1][2] += k1 * v0.z; dacc[1][3] += k1 * v0.w;
      dacc[1][4] += k1 * v1.x; dacc[1][5] += k1 * v1.y;
      dacc[1][6] += k1 * v1.z; dacc[1][7] += k1 * v1.w;
    }
    __syncthreads();
  }

  float* dp = dots + (size_t)(b * NH + h) * DH * DH;
#pragma unroll
  for (int p = 0; p < 2; ++p)
#pragma unroll
    for (int q = 0; q < 8; ++q)
      atomicAdd(&dp[(dg * 2 + p) * 64 + eg * 8 + q], dacc[p][q]);
}

// ---------------------------------------------------------------------------
// Kernel 2a: T[bh][c][e] = sum_d Wq_h[c][d] * dots[b,h][d][e]
// ---------------------------------------------------------------------------
__global__ __launch_bounds__(256) void t_kernel(const float* __restrict__ wqkv,
                                                const float* __restrict__ dots,
                                                float* __restrict__ T) {
  __shared__ float ds[64 * 66];
  const int bh = blockIdx.x;
  const int h = bh & 7;
  for (int i = threadIdx.x; i < 4096; i += 256) ds[(i >> 6) * 66 + (i & 63)] = dots[(size_t)bh * 4096 + i];
  __syncthreads();
  const int c = threadIdx.x & 127;
  const int e0 = (threadIdx.x >> 7) * 32;
  float acc[32];
#pragma unroll
  for (int q = 0; q < 32; ++q) acc[q] = 0.f;
  for (int d = 0; d < 64; ++d) {
    const float wq = wqkv[(size_t)c * 1536 + h * 64 + d];
#pragma unroll
    for (int q = 0; q < 32; ++q) acc[q] += wq * ds[d * 66 + e0 + q];
  }
  float* tp = T + ((size_t)bh * 128 + c) * 64 + e0;
#pragma unroll
  for (int q = 0; q < 32; ++q) tp[q] = acc[q];
}

// ---------------------------------------------------------------------------
// Kernel 2b: BigW[b][c][j] = (1/n) * sum_{h,e} T[bh][c][e] * wout[h*64+e][j]
// ---------------------------------------------------------------------------
__global__ __launch_bounds__(256) void bigw_kernel(const float* __restrict__ T,
                                                   const float* __restrict__ wout,
                                                   float* __restrict__ bigw) {
  const int b = blockIdx.x >> 2;
  const int cchunk = blockIdx.x & 3;
  const int crel = threadIdx.x >> 3;
  const int c = cchunk * 32 + crel;
  const int j0 = (threadIdx.x & 7) * 16;
  float acc[16];
#pragma unroll
  for (int q = 0; q < 16; ++q) acc[q] = 0.f;
  for (int h = 0; h < 8; ++h) {
    const float* tb = T + ((size_t)(b * 8 + h) * 128 + c) * 64;
    for (int e = 0; e < 64; ++e) {
      const float tv = tb[e];
      const float* wp = wout + (size_t)(h * 64 + e) * 128 + j0;
      const float4 w0 = *(const float4*)(wp + 0);
      const float4 w1 = *(const float4*)(wp + 4);
      const float4 w2 = *(const float4*)(wp + 8);
      const float4 w3 = *(const float4*)(wp + 12);
      acc[0] += tv * w0.x;  acc[1] += tv * w0.y;  acc[2] += tv * w0.z;  acc[3] += tv * w0.w;
      acc[4] += tv * w1.x;  acc[5] += tv * w1.y;  acc[6] += tv * w1.z;  acc[7] += tv * w1.w;
      acc[8] += tv * w2.x;  acc[9] += tv * w2.y;  acc[10] += tv * w2.z; acc[11] += tv * w2.w;
      acc[12] += tv * w3.x; acc[13] += tv * w3.y; acc[14] += tv * w3.z; acc[15] += tv * w3.w;
    }
  }
  float* bp = bigw + ((size_t)b * 128 + c) * 128 + j0;
  const float inv_n = 1.f / (float)NN;
#pragma unroll
  for (int q = 0; q < 16; ++q) bp[q] = acc[q] * inv_n;
}

// ---------------------------------------------------------------------------
// Kernel 3: out[b][row][j] = sum_c x[b][row][c] * BigW[b][c][j] + bias[j]
// ---------------------------------------------------------------------------
__global__ __launch_bounds__(256) void out_kernel(const float* __restrict__ x,
                                                  const float* __restrict__ bigw,
                                                  const float* __restrict__ bout,
                                                  float* __restrict__ out) {
  __shared__ __align__(16) float xs[64 * 32];
  __shared__ __align__(16) float ws[128 * 36];

  const int t = threadIdx.x;
  const int bx = blockIdx.x;
  const int b = bx >> 6;
  const int row0 = (bx & 63) * 128;

  const int rg = t >> 4;
  const int cg = t & 15;
  const int sr = t >> 2;
  const int skb = (t & 3) * 8;
  const int xsw = (sr & 7) << 2;

  float bias[8];
#pragma unroll
  for (int j = 0; j < 8; ++j) bias[j] = bout[cg + 16 * j];

  for (int tile = 0; tile < 2; ++tile) {
    const int rowbase = row0 + tile * 64;
    float acc[4][8];
#pragma unroll
    for (int i = 0; i < 4; ++i)
#pragma unroll
      for (int j = 0; j < 8; ++j) acc[i][j] = 0.f;

    for (int ks = 0; ks < 4; ++ks) {
      {
        const float* gp = x + (size_t)(b * NN + rowbase + sr) * DIM + ks * 32 + skb;
        const float4 v0 = *(const float4*)gp;
        const float4 v1 = *(const float4*)(gp + 4);
        *(float4*)&xs[sr * 32 + (skb ^ xsw)] = v0;
        *(float4*)&xs[sr * 32 + ((skb + 4) ^ xsw)] = v1;
      }
#pragma unroll
      for (int m = 0; m < 16; ++m) {
        const int idx = t + 256 * m;
        const int jcol = idx & 127;
        const int kk = idx >> 7;
        ws[jcol * 36 + kk] = bigw[((size_t)b * 128 + ks * 32 + kk) * 128 + jcol];
      }
      __syncthreads();

#pragma unroll
      for (int kk = 0; kk < 32; kk += 4) {
        float4 a[4];
#pragma unroll
        for (int i = 0; i < 4; ++i) {
          const int r = rg + 16 * i;
          a[i] = *(const float4*)&xs[r * 32 + (kk ^ ((r & 7) << 2))];
        }
#pragma unroll
        for (int j = 0; j < 8; ++j) {
          const float4 bv = *(const float4*)&ws[(cg + 16 * j) * 36 + kk];
#pragma unroll
          for (int i = 0; i < 4; ++i) {
            acc[i][j] += a[i].x * bv.x + a[i].y * bv.y + a[i].z * bv.z + a[i].w * bv.w;
          }
        }
      }
      __syncthreads();
    }

#pragma unroll
    for (int i = 0; i < 4; ++i) {
      const int r = rowbase + rg + 16 * i;
#pragma unroll
      for (int j = 0; j < 8; ++j) {
        out[(size_t)(b * NN + r) * DIM + cg + 16 * j] = acc[i][j] + bias[j];
      }
    }
  }
}

extern "C" void kernel_launch(void* const* d_in, const int* in_sizes, int n_in,
                              void* d_out, int out_size, void* d_ws, size_t ws_size,
                              hipStream_t stream) {
  (void)in_sizes; (void)n_in; (void)out_size; (void)ws_size;
  const float* x = (const float*)d_in[0];
  const float* wqkv = (const float*)d_in[1];
  const float* wout = (const float*)d_in[2];
  const float* bout = (const float*)d_in[3];
  float* out = (float*)d_out;

  float* dots = (float*)d_ws;          // 4*8*64*64 = 131072 floats
  float* T = dots + 131072;            // 32*128*64 = 262144 floats
  float* bigw = T + 262144;            // 4*128*128 = 65536 floats

  hipMemsetAsync(dots, 0, 131072 * sizeof(float), stream);
  hipLaunchKernelGGL(kv_dots_kernel, dim3(512), dim3(256), 0, stream, x, wqkv, dots);
  hipLaunchKernelGGL(t_kernel, dim3(32), dim3(256), 0, stream, wqkv, dots, T);
  hipLaunchKernelGGL(bigw_kernel, dim3(16), dim3(256), 0, stream, T, wout, bigw);
  hipLaunchKernelGGL(out_kernel, dim3(256), dim3(256), 0, stream, x, bigw, bout, out);
}

// Round 2
// 235.166 us; speedup vs baseline: 2.5741x; 2.5741x over previous
//
#include <hip/hip_runtime.h>

#define NN 8192
#define DIM 128

typedef short short8 __attribute__((ext_vector_type(8)));
typedef float f32x4 __attribute__((ext_vector_type(4)));

__device__ __forceinline__ unsigned short f2bf(float f) {
  unsigned int u = __float_as_uint(f);
  u = (u + 0x7FFFu + ((u >> 16) & 1u)) >> 16;
  return (unsigned short)u;
}
__device__ __forceinline__ unsigned int packbf(float a, float b) {
  return (unsigned int)f2bf(a) | ((unsigned int)f2bf(b) << 16);
}

// ---------------------------------------------------------------------------
// K1: per (b, h, chunk of 512 rows):
//   kv = bf16(x_rows) @ bf16(W_{k,v})  via MFMA 16x16x32
//   InstanceNorm (fp32 stats, in-register on C-fragments)
//   dots[b,h] += k^T v via MFMA on normalized bf16 kT/vT staged in LDS
// LDS: [0,8192) kT | [8192,16384) vT  (union with x tile [0,16384))
//      [16384,49152) Wkv^T bf16, XOR-swizzled
// ---------------------------------------------------------------------------
__global__ __launch_bounds__(256) void kv_dots_kernel(const float* __restrict__ x,
                                                      const float* __restrict__ wqkv,
                                                      float* __restrict__ dots) {
  __shared__ __align__(16) unsigned char smem[49152];
  unsigned char* const XB = smem;          // x tile bf16 [64][128], pitch 256B, swizzled
  unsigned char* const KT = smem;          // kT bf16 [64 d][64 row], pitch 128B, swizzled
  unsigned char* const VT = smem + 8192;   // vT bf16 [64 e][64 row]
  unsigned char* const WB = smem + 16384;  // W^T bf16 [128 c][128 k], pitch 256B, swizzled

  const int t = threadIdx.x;
  const int bx = blockIdx.x;
  const int chunk = bx & 15;
  const int h = (bx >> 4) & 7;
  const int b = bx >> 7;
  const int row0 = chunk * 512;

  const int wave = t >> 6;
  const int lane = t & 63;
  const int lb = lane & 15;
  const int kg = lane >> 4;
  const unsigned int lxor = (unsigned int)(lb & 7) << 4;

  // ---- stage W^T for this head, once per block ----
  {
    const int k = t >> 1;        // 0..127
    const int chalf = t & 1;     // 0: k-cols, 1: v-cols
    const float* wp = wqkv + (size_t)k * 1536 + (chalf ? (1024 + h * 64) : (512 + h * 64));
    const float4* wp4 = (const float4*)wp;
    const int c0 = chalf * 64;
#pragma unroll
    for (int jj = 0; jj < 16; ++jj) {
      const float4 v = wp4[jj];
      const int c = c0 + jj * 4;
      const unsigned int cx0 = (unsigned int)((c + 0) & 7) << 4;
      const unsigned int cx1 = (unsigned int)((c + 1) & 7) << 4;
      const unsigned int cx2 = (unsigned int)((c + 2) & 7) << 4;
      const unsigned int cx3 = (unsigned int)((c + 3) & 7) << 4;
      *(unsigned short*)(WB + (c + 0) * 256 + (((unsigned)(2 * k)) ^ cx0)) = f2bf(v.x);
      *(unsigned short*)(WB + (c + 1) * 256 + (((unsigned)(2 * k)) ^ cx1)) = f2bf(v.y);
      *(unsigned short*)(WB + (c + 2) * 256 + (((unsigned)(2 * k)) ^ cx2)) = f2bf(v.z);
      *(unsigned short*)(WB + (c + 3) * 256 + (((unsigned)(2 * k)) ^ cx3)) = f2bf(v.w);
    }
  }

  f32x4 dacc[4];
#pragma unroll
  for (int nt = 0; nt < 4; ++nt) dacc[nt] = (f32x4)0.f;

  __syncthreads();

  for (int tile = 0; tile < 8; ++tile) {
    const int rowbase = row0 + tile * 64;

    // ---- barrier: previous iter's dots reads of KT/VT done ----
    __syncthreads();

    // ---- stage x tile -> bf16, swizzled ----
    {
      const int r = t >> 2;
      const int cb = (t & 3) * 32;
      const float4* gp4 = (const float4*)(x + (size_t)(b * NN + rowbase + r) * DIM + cb);
      const unsigned int rxor = (unsigned int)(r & 7) << 4;
#pragma unroll
      for (int jj = 0; jj < 4; ++jj) {
        const float4 v0 = gp4[2 * jj];
        const float4 v1 = gp4[2 * jj + 1];
        uint4 u;
        u.x = packbf(v0.x, v0.y);
        u.y = packbf(v0.z, v0.w);
        u.z = packbf(v1.x, v1.y);
        u.w = packbf(v1.z, v1.w);
        *(uint4*)(XB + r * 256 + (((unsigned)(2 * cb + 16 * jj)) ^ rxor)) = u;
      }
    }
    __syncthreads();

    // ---- kv = x @ W via MFMA: wave owns rows [16w,16w+16), all 128 cols ----
    f32x4 acc[8];
#pragma unroll
    for (int ct = 0; ct < 8; ++ct) acc[ct] = (f32x4)0.f;

    const int arow = wave * 16 + lb;
#pragma unroll
    for (int ks = 0; ks < 4; ++ks) {
      const unsigned int koff = (unsigned int)(ks * 64 + kg * 16);
      const short8 a = *(const short8*)(XB + arow * 256 + (koff ^ lxor));
#pragma unroll
      for (int ct = 0; ct < 8; ++ct) {
        const short8 bf = *(const short8*)(WB + (ct * 16 + lb) * 256 + (koff ^ lxor));
        acc[ct] = __builtin_amdgcn_mfma_f32_16x16x32_bf16(a, bf, acc[ct], 0, 0, 0);
      }
    }

    // ---- InstanceNorm in registers: rows = 16w + kg*4 + e ----
    float mk[4], sck[4], mv[4], scv[4];
#pragma unroll
    for (int e = 0; e < 4; ++e) {
      float s1 = acc[0][e] + acc[1][e] + acc[2][e] + acc[3][e];
      float s2 = acc[0][e] * acc[0][e] + acc[1][e] * acc[1][e] +
                 acc[2][e] * acc[2][e] + acc[3][e] * acc[3][e];
      s1 += __shfl_xor(s1, 1); s2 += __shfl_xor(s2, 1);
      s1 += __shfl_xor(s1, 2); s2 += __shfl_xor(s2, 2);
      s1 += __shfl_xor(s1, 4); s2 += __shfl_xor(s2, 4);
      s1 += __shfl_xor(s1, 8); s2 += __shfl_xor(s2, 8);
      const float m = s1 * (1.f / 64.f);
      mk[e] = m;
      sck[e] = rsqrtf(s2 * (1.f / 64.f) - m * m + 1e-5f);
    }
#pragma unroll
    for (int e = 0; e < 4; ++e) {
      float s1 = acc[4][e] + acc[5][e] + acc[6][e] + acc[7][e];
      float s2 = acc[4][e] * acc[4][e] + acc[5][e] * acc[5][e] +
                 acc[6][e] * acc[6][e] + acc[7][e] * acc[7][e];
      s1 += __shfl_xor(s1, 1); s2 += __shfl_xor(s2, 1);
      s1 += __shfl_xor(s1, 2); s2 += __shfl_xor(s2, 2);
      s1 += __shfl_xor(s1, 4); s2 += __shfl_xor(s2, 4);
      s1 += __shfl_xor(s1, 8); s2 += __shfl_xor(s2, 8);
      const float m = s1 * (1.f / 64.f);
      mv[e] = m;
      scv[e] = rsqrtf(s2 * (1.f / 64.f) - m * m + 1e-5f);
    }

    __syncthreads();  // all waves done reading XB (kv MFMA) before kT/vT overwrite

    // ---- write normalized kT, vT (bf16, packed 4 rows per ds_write_b64) ----
    {
      const unsigned int rb2 = (unsigned int)(32 * wave + kg * 8);
#pragma unroll
      for (int ct = 0; ct < 4; ++ct) {
        ushort4 w;
        w.x = f2bf((acc[ct][0] - mk[0]) * sck[0]);
        w.y = f2bf((acc[ct][1] - mk[1]) * sck[1]);
        w.z = f2bf((acc[ct][2] - mk[2]) * sck[2]);
        w.w = f2bf((acc[ct][3] - mk[3]) * sck[3]);
        *(ushort4*)(KT + (ct * 16 + lb) * 128 + (rb2 ^ lxor)) = w;
      }
#pragma unroll
      for (int ct = 4; ct < 8; ++ct) {
        ushort4 w;
        w.x = f2bf((acc[ct][0] - mv[0]) * scv[0]);
        w.y = f2bf((acc[ct][1] - mv[1]) * scv[1]);
        w.z = f2bf((acc[ct][2] - mv[2]) * scv[2]);
        w.w = f2bf((acc[ct][3] - mv[3]) * scv[3]);
        *(ushort4*)(VT + ((ct - 4) * 16 + lb) * 128 + (rb2 ^ lxor)) = w;
      }
    }
    __syncthreads();

    // ---- dots += kT @ v : wave owns d-tile w, all 4 e-tiles ----
#pragma unroll
    for (int ks2 = 0; ks2 < 2; ++ks2) {
      const unsigned int koff = (unsigned int)(ks2 * 64 + kg * 16);
      const short8 a = *(const short8*)(KT + (wave * 16 + lb) * 128 + (koff ^ lxor));
#pragma unroll
      for (int nt = 0; nt < 4; ++nt) {
        const short8 bf = *(const short8*)(VT + (nt * 16 + lb) * 128 + (koff ^ lxor));
        dacc[nt] = __builtin_amdgcn_mfma_f32_16x16x32_bf16(a, bf, dacc[nt], 0, 0, 0);
      }
    }
  }

  // ---- accumulate into global dots ----
  float* dp = dots + (size_t)(b * 8 + h) * 4096;
#pragma unroll
  for (int nt = 0; nt < 4; ++nt) {
#pragma unroll
    for (int reg = 0; reg < 4; ++reg) {
      const int d = 16 * wave + kg * 4 + reg;
      const int e = nt * 16 + lb;
      atomicAdd(&dp[d * 64 + e], dacc[nt][reg]);
    }
  }
}

// ---------------------------------------------------------------------------
// Kernel 2a: T[bh][c][e] = sum_d Wq_h[c][d] * dots[b,h][d][e]
// ---------------------------------------------------------------------------
__global__ __launch_bounds__(256) void t_kernel(const float* __restrict__ wqkv,
                                                const float* __restrict__ dots,
                                                float* __restrict__ T) {
  __shared__ float ds[64 * 66];
  const int bh = blockIdx.x;
  const int h = bh & 7;
  for (int i = threadIdx.x; i < 4096; i += 256) ds[(i >> 6) * 66 + (i & 63)] = dots[(size_t)bh * 4096 + i];
  __syncthreads();
  const int c = threadIdx.x & 127;
  const int e0 = (threadIdx.x >> 7) * 32;
  float acc[32];
#pragma unroll
  for (int q = 0; q < 32; ++q) acc[q] = 0.f;
  for (int d = 0; d < 64; ++d) {
    const float wq = wqkv[(size_t)c * 1536 + h * 64 + d];
#pragma unroll
    for (int q = 0; q < 32; ++q) acc[q] += wq * ds[d * 66 + e0 + q];
  }
  float* tp = T + ((size_t)bh * 128 + c) * 64 + e0;
#pragma unroll
  for (int q = 0; q < 32; ++q) tp[q] = acc[q];
}

// ---------------------------------------------------------------------------
// Kernel 2b: BigW[b][c][j] = (1/n) * sum_{h,e} T[bh][c][e] * wout[h*64+e][j]
// ---------------------------------------------------------------------------
__global__ __launch_bounds__(256) void bigw_kernel(const float* __restrict__ T,
                                                   const float* __restrict__ wout,
                                                   float* __restrict__ bigw) {
  const int b = blockIdx.x >> 2;
  const int cchunk = blockIdx.x & 3;
  const int crel = threadIdx.x >> 3;
  const int c = cchunk * 32 + crel;
  const int j0 = (threadIdx.x & 7) * 16;
  float acc[16];
#pragma unroll
  for (int q = 0; q < 16; ++q) acc[q] = 0.f;
  for (int h = 0; h < 8; ++h) {
    const float* tb = T + ((size_t)(b * 8 + h) * 128 + c) * 64;
    for (int e = 0; e < 64; ++e) {
      const float tv = tb[e];
      const float* wp = wout + (size_t)(h * 64 + e) * 128 + j0;
      const float4 w0 = *(const float4*)(wp + 0);
      const float4 w1 = *(const float4*)(wp + 4);
      const float4 w2 = *(const float4*)(wp + 8);
      const float4 w3 = *(const float4*)(wp + 12);
      acc[0] += tv * w0.x;  acc[1] += tv * w0.y;  acc[2] += tv * w0.z;  acc[3] += tv * w0.w;
      acc[4] += tv * w1.x;  acc[5] += tv * w1.y;  acc[6] += tv * w1.z;  acc[7] += tv * w1.w;
      acc[8] += tv * w2.x;  acc[9] += tv * w2.y;  acc[10] += tv * w2.z; acc[11] += tv * w2.w;
      acc[12] += tv * w3.x; acc[13] += tv * w3.y; acc[14] += tv * w3.z; acc[15] += tv * w3.w;
    }
  }
  float* bp = bigw + ((size_t)b * 128 + c) * 128 + j0;
  const float inv_n = 1.f / (float)NN;
#pragma unroll
  for (int q = 0; q < 16; ++q) bp[q] = acc[q] * inv_n;
}

// ---------------------------------------------------------------------------
// Kernel 3: out[b][row][j] = sum_c x[b][row][c] * BigW[b][c][j] + bias[j]
// ---------------------------------------------------------------------------
__global__ __launch_bounds__(256) void out_kernel(const float* __restrict__ x,
                                                  const float* __restrict__ bigw,
                                                  const float* __restrict__ bout,
                                                  float* __restrict__ out) {
  __shared__ __align__(16) float xs[64 * 32];
  __shared__ __align__(16) float ws[128 * 36];

  const int t = threadIdx.x;
  const int bx = blockIdx.x;
  const int b = bx >> 6;
  const int row0 = (bx & 63) * 128;

  const int rg = t >> 4;
  const int cg = t & 15;
  const int sr = t >> 2;
  const int skb = (t & 3) * 8;
  const int xsw = (sr & 7) << 2;

  float bias[8];
#pragma unroll
  for (int j = 0; j < 8; ++j) bias[j] = bout[cg + 16 * j];

  for (int tile = 0; tile < 2; ++tile) {
    const int rowbase = row0 + tile * 64;
    float acc[4][8];
#pragma unroll
    for (int i = 0; i < 4; ++i)
#pragma unroll
      for (int j = 0; j < 8; ++j) acc[i][j] = 0.f;

    for (int ks = 0; ks < 4; ++ks) {
      {
        const float* gp = x + (size_t)(b * NN + rowbase + sr) * DIM + ks * 32 + skb;
        const float4 v0 = *(const float4*)gp;
        const float4 v1 = *(const float4*)(gp + 4);
        *(float4*)&xs[sr * 32 + (skb ^ xsw)] = v0;
        *(float4*)&xs[sr * 32 + ((skb + 4) ^ xsw)] = v1;
      }
#pragma unroll
      for (int m = 0; m < 16; ++m) {
        const int idx = t + 256 * m;
        const int jcol = idx & 127;
        const int kk = idx >> 7;
        ws[jcol * 36 + kk] = bigw[((size_t)b * 128 + ks * 32 + kk) * 128 + jcol];
      }
      __syncthreads();

#pragma unroll
      for (int kk = 0; kk < 32; kk += 4) {
        float4 a[4];
#pragma unroll
        for (int i = 0; i < 4; ++i) {
          const int r = rg + 16 * i;
          a[i] = *(const float4*)&xs[r * 32 + (kk ^ ((r & 7) << 2))];
        }
#pragma unroll
        for (int j = 0; j < 8; ++j) {
          const float4 bv = *(const float4*)&ws[(cg + 16 * j) * 36 + kk];
#pragma unroll
          for (int i = 0; i < 4; ++i) {
            acc[i][j] += a[i].x * bv.x + a[i].y * bv.y + a[i].z * bv.z + a[i].w * bv.w;
          }
        }
      }
      __syncthreads();
    }

#pragma unroll
    for (int i = 0; i < 4; ++i) {
      const int r = rowbase + rg + 16 * i;
#pragma unroll
      for (int j = 0; j < 8; ++j) {
        out[(size_t)(b * NN + r) * DIM + cg + 16 * j] = acc[i][j] + bias[j];
      }
    }
  }
}

extern "C" void kernel_launch(void* const* d_in, const int* in_sizes, int n_in,
                              void* d_out, int out_size, void* d_ws, size_t ws_size,
                              hipStream_t stream) {
  (void)in_sizes; (void)n_in; (void)out_size; (void)ws_size;
  const float* x = (const float*)d_in[0];
  const float* wqkv = (const float*)d_in[1];
  const float* wout = (const float*)d_in[2];
  const float* bout = (const float*)d_in[3];
  float* out = (float*)d_out;

  float* dots = (float*)d_ws;          // 4*8*64*64 = 131072 floats
  float* T = dots + 131072;            // 32*128*64 = 262144 floats
  float* bigw = T + 262144;            // 4*128*128 = 65536 floats

  hipMemsetAsync(dots, 0, 131072 * sizeof(float), stream);
  hipLaunchKernelGGL(kv_dots_kernel, dim3(512), dim3(256), 0, stream, x, wqkv, dots);
  hipLaunchKernelGGL(t_kernel, dim3(32), dim3(256), 0, stream, wqkv, dots, T);
  hipLaunchKernelGGL(bigw_kernel, dim3(16), dim3(256), 0, stream, T, wout, bigw);
  hipLaunchKernelGGL(out_kernel, dim3(256), dim3(256), 0, stream, x, bigw, bout, out);
}

// Round 5
// 97.687 us; speedup vs baseline: 6.1966x; 2.4073x over previous
//
#include <hip/hip_runtime.h>

#define NN 8192
#define DIM 128

typedef short short8 __attribute__((ext_vector_type(8)));
typedef float f32x4 __attribute__((ext_vector_type(4)));

__device__ __forceinline__ unsigned short f2bf(float f) {
  unsigned int u = __float_as_uint(f);
  u = (u + 0x7FFFu + ((u >> 16) & 1u)) >> 16;
  return (unsigned short)u;
}
__device__ __forceinline__ unsigned int packbf(float a, float b) {
  return (unsigned int)f2bf(a) | ((unsigned int)f2bf(b) << 16);
}

// ---------------------------------------------------------------------------
// K1: per (b, h, chunk of 512 rows):
//   kv = bf16(x_rows) @ bf16(W_{k,v})  via MFMA 16x16x32
//   InstanceNorm (fp32 stats, in-register on C-fragments)
//   dots[b,h] += k^T v via MFMA on normalized bf16 kT/vT staged in LDS
// ---------------------------------------------------------------------------
__global__ __launch_bounds__(256) void kv_dots_kernel(const float* __restrict__ x,
                                                      const float* __restrict__ wqkv,
                                                      float* __restrict__ dots) {
  __shared__ __align__(16) unsigned char smem[49152];
  unsigned char* const XB = smem;          // x tile bf16 [64][128], pitch 256B, swizzled
  unsigned char* const KT = smem;          // kT bf16 [64 d][64 row], pitch 128B, swizzled
  unsigned char* const VT = smem + 8192;   // vT bf16 [64 e][64 row]
  unsigned char* const WB = smem + 16384;  // W^T bf16 [128 c][128 k], pitch 256B, swizzled

  const int t = threadIdx.x;
  const int bx = blockIdx.x;
  const int chunk = bx & 15;
  const int h = (bx >> 4) & 7;
  const int b = bx >> 7;
  const int row0 = chunk * 512;

  const int wave = t >> 6;
  const int lane = t & 63;
  const int lb = lane & 15;
  const int kg = lane >> 4;
  const unsigned int lxor = (unsigned int)(lb & 7) << 4;

  // ---- stage W^T for this head, once per block ----
  {
    const int k = t >> 1;        // 0..127
    const int chalf = t & 1;     // 0: k-cols, 1: v-cols
    const float* wp = wqkv + (size_t)k * 1536 + (chalf ? (1024 + h * 64) : (512 + h * 64));
    const float4* wp4 = (const float4*)wp;
    const int c0 = chalf * 64;
#pragma unroll
    for (int jj = 0; jj < 16; ++jj) {
      const float4 v = wp4[jj];
      const int c = c0 + jj * 4;
      const unsigned int cx0 = (unsigned int)((c + 0) & 7) << 4;
      const unsigned int cx1 = (unsigned int)((c + 1) & 7) << 4;
      const unsigned int cx2 = (unsigned int)((c + 2) & 7) << 4;
      const unsigned int cx3 = (unsigned int)((c + 3) & 7) << 4;
      *(unsigned short*)(WB + (c + 0) * 256 + (((unsigned)(2 * k)) ^ cx0)) = f2bf(v.x);
      *(unsigned short*)(WB + (c + 1) * 256 + (((unsigned)(2 * k)) ^ cx1)) = f2bf(v.y);
      *(unsigned short*)(WB + (c + 2) * 256 + (((unsigned)(2 * k)) ^ cx2)) = f2bf(v.z);
      *(unsigned short*)(WB + (c + 3) * 256 + (((unsigned)(2 * k)) ^ cx3)) = f2bf(v.w);
    }
  }

  f32x4 dacc[4];
#pragma unroll
  for (int nt = 0; nt < 4; ++nt) dacc[nt] = (f32x4)0.f;

  __syncthreads();

  for (int tile = 0; tile < 8; ++tile) {
    const int rowbase = row0 + tile * 64;

    __syncthreads();

    // ---- stage x tile -> bf16, swizzled ----
    {
      const int r = t >> 2;
      const int cb = (t & 3) * 32;
      const float4* gp4 = (const float4*)(x + (size_t)(b * NN + rowbase + r) * DIM + cb);
      const unsigned int rxor = (unsigned int)(r & 7) << 4;
#pragma unroll
      for (int jj = 0; jj < 4; ++jj) {
        const float4 v0 = gp4[2 * jj];
        const float4 v1 = gp4[2 * jj + 1];
        uint4 u;
        u.x = packbf(v0.x, v0.y);
        u.y = packbf(v0.z, v0.w);
        u.z = packbf(v1.x, v1.y);
        u.w = packbf(v1.z, v1.w);
        *(uint4*)(XB + r * 256 + (((unsigned)(2 * cb + 16 * jj)) ^ rxor)) = u;
      }
    }
    __syncthreads();

    // ---- kv = x @ W via MFMA ----
    f32x4 acc[8];
#pragma unroll
    for (int ct = 0; ct < 8; ++ct) acc[ct] = (f32x4)0.f;

    const int arow = wave * 16 + lb;
#pragma unroll
    for (int ks = 0; ks < 4; ++ks) {
      const unsigned int koff = (unsigned int)(ks * 64 + kg * 16);
      const short8 a = *(const short8*)(XB + arow * 256 + (koff ^ lxor));
#pragma unroll
      for (int ct = 0; ct < 8; ++ct) {
        const short8 bf = *(const short8*)(WB + (ct * 16 + lb) * 256 + (koff ^ lxor));
        acc[ct] = __builtin_amdgcn_mfma_f32_16x16x32_bf16(a, bf, acc[ct], 0, 0, 0);
      }
    }

    // ---- InstanceNorm in registers ----
    float mk[4], sck[4], mv[4], scv[4];
#pragma unroll
    for (int e = 0; e < 4; ++e) {
      float s1 = acc[0][e] + acc[1][e] + acc[2][e] + acc[3][e];
      float s2 = acc[0][e] * acc[0][e] + acc[1][e] * acc[1][e] +
                 acc[2][e] * acc[2][e] + acc[3][e] * acc[3][e];
      s1 += __shfl_xor(s1, 1); s2 += __shfl_xor(s2, 1);
      s1 += __shfl_xor(s1, 2); s2 += __shfl_xor(s2, 2);
      s1 += __shfl_xor(s1, 4); s2 += __shfl_xor(s2, 4);
      s1 += __shfl_xor(s1, 8); s2 += __shfl_xor(s2, 8);
      const float m = s1 * (1.f / 64.f);
      mk[e] = m;
      sck[e] = rsqrtf(s2 * (1.f / 64.f) - m * m + 1e-5f);
    }
#pragma unroll
    for (int e = 0; e < 4; ++e) {
      float s1 = acc[4][e] + acc[5][e] + acc[6][e] + acc[7][e];
      float s2 = acc[4][e] * acc[4][e] + acc[5][e] * acc[5][e] +
                 acc[6][e] * acc[6][e] + acc[7][e] * acc[7][e];
      s1 += __shfl_xor(s1, 1); s2 += __shfl_xor(s2, 1);
      s1 += __shfl_xor(s1, 2); s2 += __shfl_xor(s2, 2);
      s1 += __shfl_xor(s1, 4); s2 += __shfl_xor(s2, 4);
      s1 += __shfl_xor(s1, 8); s2 += __shfl_xor(s2, 8);
      const float m = s1 * (1.f / 64.f);
      mv[e] = m;
      scv[e] = rsqrtf(s2 * (1.f / 64.f) - m * m + 1e-5f);
    }

    __syncthreads();

    // ---- write normalized kT, vT ----
    {
      const unsigned int rb2 = (unsigned int)(32 * wave + kg * 8);
#pragma unroll
      for (int ct = 0; ct < 4; ++ct) {
        ushort4 w;
        w.x = f2bf((acc[ct][0] - mk[0]) * sck[0]);
        w.y = f2bf((acc[ct][1] - mk[1]) * sck[1]);
        w.z = f2bf((acc[ct][2] - mk[2]) * sck[2]);
        w.w = f2bf((acc[ct][3] - mk[3]) * sck[3]);
        *(ushort4*)(KT + (ct * 16 + lb) * 128 + (rb2 ^ lxor)) = w;
      }
#pragma unroll
      for (int ct = 4; ct < 8; ++ct) {
        ushort4 w;
        w.x = f2bf((acc[ct][0] - mv[0]) * scv[0]);
        w.y = f2bf((acc[ct][1] - mv[1]) * scv[1]);
        w.z = f2bf((acc[ct][2] - mv[2]) * scv[2]);
        w.w = f2bf((acc[ct][3] - mv[3]) * scv[3]);
        *(ushort4*)(VT + ((ct - 4) * 16 + lb) * 128 + (rb2 ^ lxor)) = w;
      }
    }
    __syncthreads();

    // ---- dots += kT @ v ----
#pragma unroll
    for (int ks2 = 0; ks2 < 2; ++ks2) {
      const unsigned int koff = (unsigned int)(ks2 * 64 + kg * 16);
      const short8 a = *(const short8*)(KT + (wave * 16 + lb) * 128 + (koff ^ lxor));
#pragma unroll
      for (int nt = 0; nt < 4; ++nt) {
        const short8 bf = *(const short8*)(VT + (nt * 16 + lb) * 128 + (koff ^ lxor));
        dacc[nt] = __builtin_amdgcn_mfma_f32_16x16x32_bf16(a, bf, dacc[nt], 0, 0, 0);
      }
    }
  }

  float* dp = dots + (size_t)(b * 8 + h) * 4096;
#pragma unroll
  for (int nt = 0; nt < 4; ++nt) {
#pragma unroll
    for (int reg = 0; reg < 4; ++reg) {
      const int d = 16 * wave + kg * 4 + reg;
      const int e = nt * 16 + lb;
      atomicAdd(&dp[d * 64 + e], dacc[nt][reg]);
    }
  }
}

// ---------------------------------------------------------------------------
// K2 (fused t + bigw): per (b,h) block:
//   T = Wq_h @ dots[b,h]           (128x64, K=64)  -- all in LDS
//   part[b,h] = T @ Wout_h         (128x128, K=64) -- written to ws
// ---------------------------------------------------------------------------
__global__ __launch_bounds__(256) void tw_kernel(const float* __restrict__ wqkv,
                                                 const float* __restrict__ wout,
                                                 const float* __restrict__ dots,
                                                 float* __restrict__ part) {
  __shared__ __align__(16) float ds[64 * 66];    // dots [d][e]
  __shared__ __align__(16) float wqT[64 * 130];  // Wq^T [d][c]
  __shared__ __align__(16) float Ts[128 * 66];   // T [c][e]
  __shared__ __align__(16) float wos[64 * 132];  // Wout rows [e][j]

  const int bh = blockIdx.x;
  const int h = bh & 7;
  const int t = threadIdx.x;

  for (int i = t; i < 4096; i += 256)
    ds[(i >> 6) * 66 + (i & 63)] = dots[(size_t)bh * 4096 + i];

  {
    const int c = t >> 1, half = t & 1;
    const float4* wp4 = (const float4*)(wqkv + (size_t)c * 1536 + h * 64 + half * 32);
#pragma unroll
    for (int q = 0; q < 8; ++q) {
      const float4 v = wp4[q];
      const int d = half * 32 + q * 4;
      wqT[(d + 0) * 130 + c] = v.x;
      wqT[(d + 1) * 130 + c] = v.y;
      wqT[(d + 2) * 130 + c] = v.z;
      wqT[(d + 3) * 130 + c] = v.w;
    }
  }

  for (int i = t; i < 2048; i += 256) {  // i indexes float4 of wout block
    const int e = i >> 5;
    const int jj = (i & 31) * 4;
    *(float4*)&wos[e * 132 + jj] = *(const float4*)(wout + (size_t)(h * 64 + e) * 128 + jj);
  }
  __syncthreads();

  // phase 1: Ts[c][e] = sum_d wqT[d][c] * ds[d][e]
  {
    const int c = t >> 1, e0 = (t & 1) * 32;
    float acc[32];
#pragma unroll
    for (int q = 0; q < 32; ++q) acc[q] = 0.f;
    for (int d = 0; d < 64; ++d) {
      const float wq = wqT[d * 130 + c];
#pragma unroll
      for (int q = 0; q < 32; q += 4) {
        const float4 dv = *(const float4*)&ds[d * 66 + e0 + q];
        acc[q + 0] += wq * dv.x;
        acc[q + 1] += wq * dv.y;
        acc[q + 2] += wq * dv.z;
        acc[q + 3] += wq * dv.w;
      }
    }
#pragma unroll
    for (int q = 0; q < 32; q += 4)
      *(float4*)&Ts[c * 66 + e0 + q] = make_float4(acc[q], acc[q + 1], acc[q + 2], acc[q + 3]);
  }
  __syncthreads();

  // phase 2: part[c][j] = sum_e Ts[c][e] * wos[e][j]
  {
    const int c = t >> 1;
    const int j0 = (t & 1) * 64;
    float acc[64];
#pragma unroll
    for (int q = 0; q < 64; ++q) acc[q] = 0.f;
    for (int e = 0; e < 64; ++e) {
      const float tv = Ts[c * 66 + e];
#pragma unroll
      for (int q = 0; q < 64; q += 4) {
        const float4 wv = *(const float4*)&wos[e * 132 + j0 + q];
        acc[q + 0] += tv * wv.x;
        acc[q + 1] += tv * wv.y;
        acc[q + 2] += tv * wv.z;
        acc[q + 3] += tv * wv.w;
      }
    }
    float* pp = part + (size_t)bh * 16384 + (size_t)c * 128 + j0;
#pragma unroll
    for (int q = 0; q < 64; q += 4)
      *(float4*)&pp[q] = make_float4(acc[q], acc[q + 1], acc[q + 2], acc[q + 3]);
  }
}

// ---------------------------------------------------------------------------
// K2r: bigw[b][cj] = (1/n) * sum_h part[b*8+h][cj]
// ---------------------------------------------------------------------------
__global__ __launch_bounds__(256) void bigw_reduce(const float* __restrict__ part,
                                                   float* __restrict__ bigw) {
  const int i = blockIdx.x * 256 + threadIdx.x;  // 0..65535
  const int b = i >> 14;
  const int cj = i & 16383;
  const float* pp = part + (size_t)b * 8 * 16384 + cj;
  float s = 0.f;
#pragma unroll
  for (int h = 0; h < 8; ++h) s += pp[h * 16384];
  bigw[i] = s * (1.f / (float)NN);
}

// ---------------------------------------------------------------------------
// K3 (MFMA): out[b][row][j] = sum_c bf16(x[b][row][c]) * bf16(BigW[b][c][j]) + bias[j]
// Same GEMM structure as K1: WB = BigW^T bf16 swizzled [j][c], XB = x tile.
// ---------------------------------------------------------------------------
__global__ __launch_bounds__(256) void out_kernel(const float* __restrict__ x,
                                                  const float* __restrict__ bigw,
                                                  const float* __restrict__ bout,
                                                  float* __restrict__ out) {
  __shared__ __align__(16) unsigned char smem[49152];
  unsigned char* const XB = smem;          // x tile bf16 [64][128], pitch 256B, swizzled
  unsigned char* const WB = smem + 16384;  // BigW^T bf16 [128 j][128 c], pitch 256B, swizzled

  const int t = threadIdx.x;
  const int bx = blockIdx.x;
  const int b = bx >> 6;
  const int row0 = (bx & 63) * 128;

  const int wave = t >> 6;
  const int lane = t & 63;
  const int lb = lane & 15;
  const int kg = lane >> 4;
  const unsigned int lxor = (unsigned int)(lb & 7) << 4;

  // ---- stage BigW^T bf16 swizzled: WB[j][2c ^ ((j&7)<<4)] ----
  {
    const int c = t >> 1;        // 0..127
    const int jhalf = t & 1;     // 64 j's each
    const float4* wp4 = (const float4*)(bigw + (size_t)b * 16384 + (size_t)c * 128 + jhalf * 64);
    const int j0 = jhalf * 64;
#pragma unroll
    for (int q = 0; q < 16; ++q) {
      const float4 v = wp4[q];
      const int j = j0 + q * 4;
      const unsigned int jx0 = (unsigned int)((j + 0) & 7) << 4;
      const unsigned int jx1 = (unsigned int)((j + 1) & 7) << 4;
      const unsigned int jx2 = (unsigned int)((j + 2) & 7) << 4;
      const unsigned int jx3 = (unsigned int)((j + 3) & 7) << 4;
      *(unsigned short*)(WB + (j + 0) * 256 + (((unsigned)(2 * c)) ^ jx0)) = f2bf(v.x);
      *(unsigned short*)(WB + (j + 1) * 256 + (((unsigned)(2 * c)) ^ jx1)) = f2bf(v.y);
      *(unsigned short*)(WB + (j + 2) * 256 + (((unsigned)(2 * c)) ^ jx2)) = f2bf(v.z);
      *(unsigned short*)(WB + (j + 3) * 256 + (((unsigned)(2 * c)) ^ jx3)) = f2bf(v.w);
    }
  }

  float bias[8];
#pragma unroll
  for (int ct = 0; ct < 8; ++ct) bias[ct] = bout[ct * 16 + lb];

  __syncthreads();

  for (int tile = 0; tile < 2; ++tile) {
    const int rowbase = row0 + tile * 64;
    if (tile) __syncthreads();

    // ---- stage x tile -> bf16, swizzled ----
    {
      const int r = t >> 2;
      const int cb = (t & 3) * 32;
      const float4* gp4 = (const float4*)(x + (size_t)(b * NN + rowbase + r) * DIM + cb);
      const unsigned int rxor = (unsigned int)(r & 7) << 4;
#pragma unroll
      for (int jj = 0; jj < 4; ++jj) {
        const float4 v0 = gp4[2 * jj];
        const float4 v1 = gp4[2 * jj + 1];
        uint4 u;
        u.x = packbf(v0.x, v0.y);
        u.y = packbf(v0.z, v0.w);
        u.z = packbf(v1.x, v1.y);
        u.w = packbf(v1.z, v1.w);
        *(uint4*)(XB + r * 256 + (((unsigned)(2 * cb + 16 * jj)) ^ rxor)) = u;
      }
    }
    __syncthreads();

    // ---- out-tile = x @ BigW via MFMA ----
    f32x4 acc[8];
#pragma unroll
    for (int ct = 0; ct < 8; ++ct) acc[ct] = (f32x4)0.f;

    const int arow = wave * 16 + lb;
#pragma unroll
    for (int ks = 0; ks < 4; ++ks) {
      const unsigned int koff = (unsigned int)(ks * 64 + kg * 16);
      const short8 a = *(const short8*)(XB + arow * 256 + (koff ^ lxor));
#pragma unroll
      for (int ct = 0; ct < 8; ++ct) {
        const short8 bf = *(const short8*)(WB + (ct * 16 + lb) * 256 + (koff ^ lxor));
        acc[ct] = __builtin_amdgcn_mfma_f32_16x16x32_bf16(a, bf, acc[ct], 0, 0, 0);
      }
    }

    // ---- store with bias: row = rowbase + 16*wave + kg*4 + reg, col = ct*16+lb ----
    float* op = out + (size_t)(b * NN + rowbase + 16 * wave + kg * 4) * DIM;
#pragma unroll
    for (int ct = 0; ct < 8; ++ct) {
#pragma unroll
      for (int reg = 0; reg < 4; ++reg) {
        op[reg * DIM + ct * 16 + lb] = acc[ct][reg] + bias[ct];
      }
    }
  }
}

extern "C" void kernel_launch(void* const* d_in, const int* in_sizes, int n_in,
                              void* d_out, int out_size, void* d_ws, size_t ws_size,
                              hipStream_t stream) {
  (void)in_sizes; (void)n_in; (void)out_size; (void)ws_size;
  const float* x = (const float*)d_in[0];
  const float* wqkv = (const float*)d_in[1];
  const float* wout = (const float*)d_in[2];
  const float* bout = (const float*)d_in[3];
  float* out = (float*)d_out;

  float* dots = (float*)d_ws;          // 4*8*64*64        = 131072 floats
  float* part = dots + 131072;         // 32*128*128       = 524288 floats
  float* bigw = part + 524288;         // 4*128*128        = 65536 floats

  hipMemsetAsync(dots, 0, 131072 * sizeof(float), stream);
  hipLaunchKernelGGL(kv_dots_kernel, dim3(512), dim3(256), 0, stream, x, wqkv, dots);
  hipLaunchKernelGGL(tw_kernel, dim3(32), dim3(256), 0, stream, wqkv, wout, dots, part);
  hipLaunchKernelGGL(bigw_reduce, dim3(256), dim3(256), 0, stream, part, bigw);
  hipLaunchKernelGGL(out_kernel, dim3(256), dim3(256), 0, stream, x, bigw, bout, out);
}

// Round 6
// 79.006 us; speedup vs baseline: 7.6618x; 1.2365x over previous
//
#include <hip/hip_runtime.h>

#define NN 8192
#define DIM 128

typedef short short8 __attribute__((ext_vector_type(8)));
typedef float f32x4 __attribute__((ext_vector_type(4)));

__device__ __forceinline__ unsigned short f2bf(float f) {
  unsigned int u = __float_as_uint(f);
  u = (u + 0x7FFFu + ((u >> 16) & 1u)) >> 16;
  return (unsigned short)u;
}
// packed bf16 convert (RNE), lo = a, hi = b
__device__ __forceinline__ unsigned int cvtpk(float a, float b) {
  unsigned int r;
  asm("v_cvt_pk_bf16_f32 %0, %1, %2" : "=v"(r) : "v"(a), "v"(b));
  return r;
}

// ---------------------------------------------------------------------------
// K1: per (b, h, chunk of 256 rows):
//   kv_c = bf16(x) @ bf16(W'_{k,v})   (W' centered over dim_head -> k,v centered)
//   scale = rsqrt(ssq/64 + eps); K side scaled by s_k*s_v, V raw
//   dots[b,h] += kT @ v via MFMA
// Grid 1024; bx%8 = p%8 so all 8 heads of an x-chunk share an XCD.
// ---------------------------------------------------------------------------
__global__ __launch_bounds__(256) void kv_dots_kernel(const float* __restrict__ x,
                                                      const float* __restrict__ wqkv,
                                                      float* __restrict__ dots) {
  __shared__ __align__(16) unsigned char smem[49152];
  unsigned char* const XB = smem;          // x tile bf16 [64][128], pitch 256B, swizzled
  unsigned char* const KT = smem;          // kT bf16 [64 d][64 row], pitch 128B, swizzled
  unsigned char* const VT = smem + 8192;   // vT bf16 [64 e][64 row]
  unsigned char* const WB = smem + 16384;  // W^T bf16 [128 c][128 k], pitch 256B, swizzled

  const int t = threadIdx.x;
  const int bx = blockIdx.x;
  const int h = bx >> 7;        // 0..7
  const int p = bx & 127;       // (b, chunk)
  const int b = p >> 5;
  const int chunk = p & 31;
  const int row0 = chunk * 256;

  const int wave = t >> 6;
  const int lane = t & 63;
  const int lb = lane & 15;
  const int kg = lane >> 4;
  const unsigned int lxor = (unsigned int)(lb & 7) << 4;

  // ---- stage centered W^T for this head, once per block ----
  {
    const int k = t >> 1;        // c_in 0..127
    const int chalf = t & 1;     // 0: k-cols, 1: v-cols
    const float* wp = wqkv + (size_t)k * 1536 + (chalf ? (1024 + h * 64) : (512 + h * 64));
    const float4* wp4 = (const float4*)wp;
    const int c0 = chalf * 64;
    float4 wv[16];
    float sum = 0.f;
#pragma unroll
    for (int jj = 0; jj < 16; ++jj) {
      wv[jj] = wp4[jj];
      sum += wv[jj].x + wv[jj].y + wv[jj].z + wv[jj].w;
    }
    const float mean = sum * (1.f / 64.f);
#pragma unroll
    for (int jj = 0; jj < 16; ++jj) {
      const int c = c0 + jj * 4;
      const unsigned int cx0 = (unsigned int)((c + 0) & 7) << 4;
      const unsigned int cx1 = (unsigned int)((c + 1) & 7) << 4;
      const unsigned int cx2 = (unsigned int)((c + 2) & 7) << 4;
      const unsigned int cx3 = (unsigned int)((c + 3) & 7) << 4;
      *(unsigned short*)(WB + (c + 0) * 256 + (((unsigned)(2 * k)) ^ cx0)) = f2bf(wv[jj].x - mean);
      *(unsigned short*)(WB + (c + 1) * 256 + (((unsigned)(2 * k)) ^ cx1)) = f2bf(wv[jj].y - mean);
      *(unsigned short*)(WB + (c + 2) * 256 + (((unsigned)(2 * k)) ^ cx2)) = f2bf(wv[jj].z - mean);
      *(unsigned short*)(WB + (c + 3) * 256 + (((unsigned)(2 * k)) ^ cx3)) = f2bf(wv[jj].w - mean);
    }
  }

  f32x4 dacc[4];
#pragma unroll
  for (int nt = 0; nt < 4; ++nt) dacc[nt] = (f32x4)0.f;

  __syncthreads();

  for (int tile = 0; tile < 4; ++tile) {
    const int rowbase = row0 + tile * 64;

    __syncthreads();  // prev dots-MFMA reads of KT/VT done (alias XB)

    // ---- stage x tile -> bf16, swizzled ----
    {
      const int r = t >> 2;
      const int cb = (t & 3) * 32;
      const float4* gp4 = (const float4*)(x + (size_t)(b * NN + rowbase + r) * DIM + cb);
      const unsigned int rxor = (unsigned int)(r & 7) << 4;
#pragma unroll
      for (int jj = 0; jj < 4; ++jj) {
        const float4 v0 = gp4[2 * jj];
        const float4 v1 = gp4[2 * jj + 1];
        uint4 u;
        u.x = cvtpk(v0.x, v0.y);
        u.y = cvtpk(v0.z, v0.w);
        u.z = cvtpk(v1.x, v1.y);
        u.w = cvtpk(v1.z, v1.w);
        *(uint4*)(XB + r * 256 + (((unsigned)(2 * cb + 16 * jj)) ^ rxor)) = u;
      }
    }
    __syncthreads();

    // ---- kv_c = x @ W' via MFMA ----
    f32x4 acc[8];
#pragma unroll
    for (int ct = 0; ct < 8; ++ct) acc[ct] = (f32x4)0.f;

    const int arow = wave * 16 + lb;
#pragma unroll
    for (int ks = 0; ks < 4; ++ks) {
      const unsigned int koff = (unsigned int)(ks * 64 + kg * 16);
      const short8 a = *(const short8*)(XB + arow * 256 + (koff ^ lxor));
#pragma unroll
      for (int ct = 0; ct < 8; ++ct) {
        const short8 bf = *(const short8*)(WB + (ct * 16 + lb) * 256 + (koff ^ lxor));
        acc[ct] = __builtin_amdgcn_mfma_f32_16x16x32_bf16(a, bf, acc[ct], 0, 0, 0);
      }
    }

    // ---- variance only (centered): kscale = s_k*s_v ----
    float kscale[4];
#pragma unroll
    for (int e = 0; e < 4; ++e) {
      float sk = acc[0][e] * acc[0][e] + acc[1][e] * acc[1][e] +
                 acc[2][e] * acc[2][e] + acc[3][e] * acc[3][e];
      float sv = acc[4][e] * acc[4][e] + acc[5][e] * acc[5][e] +
                 acc[6][e] * acc[6][e] + acc[7][e] * acc[7][e];
      sk += __shfl_xor(sk, 1); sv += __shfl_xor(sv, 1);
      sk += __shfl_xor(sk, 2); sv += __shfl_xor(sv, 2);
      sk += __shfl_xor(sk, 4); sv += __shfl_xor(sv, 4);
      sk += __shfl_xor(sk, 8); sv += __shfl_xor(sv, 8);
      kscale[e] = rsqrtf(sk * (1.f / 64.f) + 1e-5f) * rsqrtf(sv * (1.f / 64.f) + 1e-5f);
    }

    __syncthreads();  // all waves done reading XB before KT/VT overwrite

    // ---- write kT (scaled) and vT (raw), bf16 ----
    {
      const unsigned int rb2 = (unsigned int)(32 * wave + kg * 8);
#pragma unroll
      for (int ct = 0; ct < 4; ++ct) {
        uint2 w;
        w.x = cvtpk(acc[ct][0] * kscale[0], acc[ct][1] * kscale[1]);
        w.y = cvtpk(acc[ct][2] * kscale[2], acc[ct][3] * kscale[3]);
        *(uint2*)(KT + (ct * 16 + lb) * 128 + (rb2 ^ lxor)) = w;
      }
#pragma unroll
      for (int ct = 4; ct < 8; ++ct) {
        uint2 w;
        w.x = cvtpk(acc[ct][0], acc[ct][1]);
        w.y = cvtpk(acc[ct][2], acc[ct][3]);
        *(uint2*)(VT + ((ct - 4) * 16 + lb) * 128 + (rb2 ^ lxor)) = w;
      }
    }
    __syncthreads();

    // ---- dots += kT @ v ----
#pragma unroll
    for (int ks2 = 0; ks2 < 2; ++ks2) {
      const unsigned int koff = (unsigned int)(ks2 * 64 + kg * 16);
      const short8 a = *(const short8*)(KT + (wave * 16 + lb) * 128 + (koff ^ lxor));
#pragma unroll
      for (int nt = 0; nt < 4; ++nt) {
        const short8 bf = *(const short8*)(VT + (nt * 16 + lb) * 128 + (koff ^ lxor));
        dacc[nt] = __builtin_amdgcn_mfma_f32_16x16x32_bf16(a, bf, dacc[nt], 0, 0, 0);
      }
    }
  }

  float* dp = dots + (size_t)(b * 8 + h) * 4096;
#pragma unroll
  for (int nt = 0; nt < 4; ++nt) {
#pragma unroll
    for (int reg = 0; reg < 4; ++reg) {
      const int d = 16 * wave + kg * 4 + reg;
      const int e = nt * 16 + lb;
      atomicAdd(&dp[d * 64 + e], dacc[nt][reg]);
    }
  }
}

// ---------------------------------------------------------------------------
// K2 (fused t + bigw), c-split: block = (bh, cq); c range = cq*32..+32
//   Ts = Wq_h[c-range] @ dots[b,h];  part[b,h][c-range] = Ts @ Wout_h
// ---------------------------------------------------------------------------
__global__ __launch_bounds__(256) void tw_kernel(const float* __restrict__ wqkv,
                                                 const float* __restrict__ wout,
                                                 const float* __restrict__ dots,
                                                 float* __restrict__ part) {
  __shared__ __align__(16) float ds[64 * 66];    // dots [d][e]
  __shared__ __align__(16) float wqT[64 * 36];   // Wq^T [d][c'] c'=0..31
  __shared__ __align__(16) float Ts[32 * 66];    // T [c'][e]
  __shared__ __align__(16) float wos[64 * 132];  // Wout rows [e][j]

  const int blk = blockIdx.x;
  const int bh = blk >> 2;
  const int cq = blk & 3;
  const int h = bh & 7;
  const int t = threadIdx.x;

  for (int i = t; i < 4096; i += 256)
    ds[(i >> 6) * 66 + (i & 63)] = dots[(size_t)bh * 4096 + i];

  for (int i = t; i < 2048; i += 256) {
    const int d = i >> 5;
    const int c = i & 31;
    wqT[d * 36 + c] = wqkv[(size_t)(cq * 32 + c) * 1536 + h * 64 + d];
  }

  for (int i = t; i < 2048; i += 256) {  // float4s of wout block
    const int e = i >> 5;
    const int jj = (i & 31) * 4;
    *(float4*)&wos[e * 132 + jj] = *(const float4*)(wout + (size_t)(h * 64 + e) * 128 + jj);
  }
  __syncthreads();

  // phase 1: Ts[c'][e] = sum_d wqT[d][c'] * ds[d][e]
  {
    const int c = t >> 3;
    const int e0 = (t & 7) * 8;
    float acc[8];
#pragma unroll
    for (int q = 0; q < 8; ++q) acc[q] = 0.f;
    for (int d = 0; d < 64; ++d) {
      const float wq = wqT[d * 36 + c];
      const float4 d0 = *(const float4*)&ds[d * 66 + e0];
      const float4 d1 = *(const float4*)&ds[d * 66 + e0 + 4];
      acc[0] += wq * d0.x; acc[1] += wq * d0.y; acc[2] += wq * d0.z; acc[3] += wq * d0.w;
      acc[4] += wq * d1.x; acc[5] += wq * d1.y; acc[6] += wq * d1.z; acc[7] += wq * d1.w;
    }
    *(float4*)&Ts[c * 66 + e0] = make_float4(acc[0], acc[1], acc[2], acc[3]);
    *(float4*)&Ts[c * 66 + e0 + 4] = make_float4(acc[4], acc[5], acc[6], acc[7]);
  }
  __syncthreads();

  // phase 2: part[c][j] = sum_e Ts[c][e] * wos[e][j]
  {
    const int c = t >> 3;
    const int j0 = (t & 7) * 16;
    float acc[16];
#pragma unroll
    for (int q = 0; q < 16; ++q) acc[q] = 0.f;
    for (int e = 0; e < 64; ++e) {
      const float tv = Ts[c * 66 + e];
#pragma unroll
      for (int q = 0; q < 16; q += 4) {
        const float4 wv = *(const float4*)&wos[e * 132 + j0 + q];
        acc[q + 0] += tv * wv.x;
        acc[q + 1] += tv * wv.y;
        acc[q + 2] += tv * wv.z;
        acc[q + 3] += tv * wv.w;
      }
    }
    float* pp = part + (size_t)bh * 16384 + (size_t)(cq * 32 + c) * 128 + j0;
#pragma unroll
    for (int q = 0; q < 16; q += 4)
      *(float4*)&pp[q] = make_float4(acc[q], acc[q + 1], acc[q + 2], acc[q + 3]);
  }
}

// ---------------------------------------------------------------------------
// K2r: bigw[b][cj] = (1/n) * sum_h part[b*8+h][cj]
// ---------------------------------------------------------------------------
__global__ __launch_bounds__(256) void bigw_reduce(const float* __restrict__ part,
                                                   float* __restrict__ bigw) {
  const int i = blockIdx.x * 256 + threadIdx.x;  // 0..65535
  const int b = i >> 14;
  const int cj = i & 16383;
  const float* pp = part + (size_t)b * 8 * 16384 + cj;
  float s = 0.f;
#pragma unroll
  for (int h = 0; h < 8; ++h) s += pp[h * 16384];
  bigw[i] = s * (1.f / (float)NN);
}

// ---------------------------------------------------------------------------
// K3 (MFMA): out = bf16(x) @ bf16(BigW_b) + bias.  Grid 512, 64-row tiles.
// ---------------------------------------------------------------------------
__global__ __launch_bounds__(256) void out_kernel(const float* __restrict__ x,
                                                  const float* __restrict__ bigw,
                                                  const float* __restrict__ bout,
                                                  float* __restrict__ out) {
  __shared__ __align__(16) unsigned char smem[49152];
  unsigned char* const XB = smem;          // x tile bf16 [64][128]
  unsigned char* const WB = smem + 16384;  // BigW^T bf16 [128 j][128 c], swizzled

  const int t = threadIdx.x;
  const int bx = blockIdx.x;
  const int b = bx >> 7;
  const int rowbase = (bx & 127) * 64;

  const int wave = t >> 6;
  const int lane = t & 63;
  const int lb = lane & 15;
  const int kg = lane >> 4;
  const unsigned int lxor = (unsigned int)(lb & 7) << 4;

  // ---- stage BigW^T bf16 swizzled ----
  {
    const int c = t >> 1;
    const int jhalf = t & 1;
    const float4* wp4 = (const float4*)(bigw + (size_t)b * 16384 + (size_t)c * 128 + jhalf * 64);
    const int j0 = jhalf * 64;
#pragma unroll
    for (int q = 0; q < 16; ++q) {
      const float4 v = wp4[q];
      const int j = j0 + q * 4;
      const unsigned int jx0 = (unsigned int)((j + 0) & 7) << 4;
      const unsigned int jx1 = (unsigned int)((j + 1) & 7) << 4;
      const unsigned int jx2 = (unsigned int)((j + 2) & 7) << 4;
      const unsigned int jx3 = (unsigned int)((j + 3) & 7) << 4;
      *(unsigned short*)(WB + (j + 0) * 256 + (((unsigned)(2 * c)) ^ jx0)) = f2bf(v.x);
      *(unsigned short*)(WB + (j + 1) * 256 + (((unsigned)(2 * c)) ^ jx1)) = f2bf(v.y);
      *(unsigned short*)(WB + (j + 2) * 256 + (((unsigned)(2 * c)) ^ jx2)) = f2bf(v.z);
      *(unsigned short*)(WB + (j + 3) * 256 + (((unsigned)(2 * c)) ^ jx3)) = f2bf(v.w);
    }
  }

  float bias[8];
#pragma unroll
  for (int ct = 0; ct < 8; ++ct) bias[ct] = bout[ct * 16 + lb];

  // ---- stage x tile -> bf16, swizzled ----
  {
    const int r = t >> 2;
    const int cb = (t & 3) * 32;
    const float4* gp4 = (const float4*)(x + (size_t)(b * NN + rowbase + r) * DIM + cb);
    const unsigned int rxor = (unsigned int)(r & 7) << 4;
#pragma unroll
    for (int jj = 0; jj < 4; ++jj) {
      const float4 v0 = gp4[2 * jj];
      const float4 v1 = gp4[2 * jj + 1];
      uint4 u;
      u.x = cvtpk(v0.x, v0.y);
      u.y = cvtpk(v0.z, v0.w);
      u.z = cvtpk(v1.x, v1.y);
      u.w = cvtpk(v1.z, v1.w);
      *(uint4*)(XB + r * 256 + (((unsigned)(2 * cb + 16 * jj)) ^ rxor)) = u;
    }
  }
  __syncthreads();

  // ---- out-tile = x @ BigW via MFMA ----
  f32x4 acc[8];
#pragma unroll
  for (int ct = 0; ct < 8; ++ct) acc[ct] = (f32x4)0.f;

  const int arow = wave * 16 + lb;
#pragma unroll
  for (int ks = 0; ks < 4; ++ks) {
    const unsigned int koff = (unsigned int)(ks * 64 + kg * 16);
    const short8 a = *(const short8*)(XB + arow * 256 + (koff ^ lxor));
#pragma unroll
    for (int ct = 0; ct < 8; ++ct) {
      const short8 bf = *(const short8*)(WB + (ct * 16 + lb) * 256 + (koff ^ lxor));
      acc[ct] = __builtin_amdgcn_mfma_f32_16x16x32_bf16(a, bf, acc[ct], 0, 0, 0);
    }
  }

  float* op = out + (size_t)(b * NN + rowbase + 16 * wave + kg * 4) * DIM;
#pragma unroll
  for (int ct = 0; ct < 8; ++ct) {
#pragma unroll
    for (int reg = 0; reg < 4; ++reg) {
      op[reg * DIM + ct * 16 + lb] = acc[ct][reg] + bias[ct];
    }
  }
}

extern "C" void kernel_launch(void* const* d_in, const int* in_sizes, int n_in,
                              void* d_out, int out_size, void* d_ws, size_t ws_size,
                              hipStream_t stream) {
  (void)in_sizes; (void)n_in; (void)out_size; (void)ws_size;
  const float* x = (const float*)d_in[0];
  const float* wqkv = (const float*)d_in[1];
  const float* wout = (const float*)d_in[2];
  const float* bout = (const float*)d_in[3];
  float* out = (float*)d_out;

  float* dots = (float*)d_ws;          // 4*8*64*64  = 131072 floats
  float* part = dots + 131072;         // 32*128*128 = 524288 floats
  float* bigw = part + 524288;         // 4*128*128  = 65536 floats

  hipMemsetAsync(dots, 0, 131072 * sizeof(float), stream);
  hipLaunchKernelGGL(kv_dots_kernel, dim3(1024), dim3(256), 0, stream, x, wqkv, dots);
  hipLaunchKernelGGL(tw_kernel, dim3(128), dim3(256), 0, stream, wqkv, wout, dots, part);
  hipLaunchKernelGGL(bigw_reduce, dim3(256), dim3(256), 0, stream, part, bigw);
  hipLaunchKernelGGL(out_kernel, dim3(512), dim3(256), 0, stream, x, bigw, bout, out);
}

// Round 7
// 75.317 us; speedup vs baseline: 8.0371x; 1.0490x over previous
//
#include <hip/hip_runtime.h>

#define NN 8192
#define DIM 128

typedef short short8 __attribute__((ext_vector_type(8)));
typedef float f32x4 __attribute__((ext_vector_type(4)));

__device__ __forceinline__ unsigned short f2bf(float f) {
  unsigned int u = __float_as_uint(f);
  u = (u + 0x7FFFu + ((u >> 16) & 1u)) >> 16;
  return (unsigned short)u;
}
__device__ __forceinline__ unsigned int cvtpk(float a, float b) {
  unsigned int r;
  asm("v_cvt_pk_bf16_f32 %0, %1, %2" : "=v"(r) : "v"(a), "v"(b));
  return r;
}
__device__ __forceinline__ void gll16(const void* gsrc, void* ldst) {
  __builtin_amdgcn_global_load_lds(
      (const __attribute__((address_space(1))) unsigned int*)gsrc,
      (__attribute__((address_space(3))) unsigned int*)ldst, 16, 0, 0);
}
#define BAR_LGKM()                                          \
  do {                                                      \
    asm volatile("s_waitcnt lgkmcnt(0)" ::: "memory");      \
    __builtin_amdgcn_sched_barrier(0);                      \
    __builtin_amdgcn_s_barrier();                           \
    __builtin_amdgcn_sched_barrier(0);                      \
  } while (0)
#define BAR_VM()                                            \
  do {                                                      \
    asm volatile("s_waitcnt vmcnt(0)" ::: "memory");        \
    __builtin_amdgcn_sched_barrier(0);                      \
    __builtin_amdgcn_s_barrier();                           \
    __builtin_amdgcn_sched_barrier(0);                      \
  } while (0)

// ---------------------------------------------------------------------------
// PREP: blocks 0..1023: x -> bf16 swizzled tile images (8 MB).
//       blocks 1024..1031: per-head centered W_kv^T bf16 swizzled image (32 KB/head).
// Image layouts match the LDS tile layouts byte-for-byte so global_load_lds
// can copy linearly (guide m173 pattern: pre-swizzled global source).
// x tile image (16 KB per (b,tile64)): byte = r*256 + ((2c) ^ ((r&7)<<4))
// W image (32 KB per head):            byte = c*256 + ((2k) ^ ((c&7)<<4))
// ---------------------------------------------------------------------------
__global__ __launch_bounds__(256) void prep_kernel(const float* __restrict__ x,
                                                   const float* __restrict__ wqkv,
                                                   unsigned char* __restrict__ ximg,
                                                   unsigned char* __restrict__ wimg) {
  __shared__ __align__(16) unsigned char wb[32768];
  const int t = threadIdx.x;
  const int bx = blockIdx.x;
  if (bx < 1024) {
#pragma unroll
    for (int rep = 0; rep < 2; ++rep) {
      const int idx = bx * 512 + rep * 256 + t;  // 16B chunk index, 0..524287
      const int bt = idx >> 10;                  // b*128 + tile
      const int o = (idx & 1023) << 4;           // byte in 16KB image
      const int r = o >> 8;
      const int q0 = o & 255;
      const int c0 = (q0 ^ ((r & 7) << 4)) >> 1;
      const float* src = x + ((size_t)(bt >> 7) * NN + (size_t)(bt & 127) * 64 + r) * DIM + c0;
      const float4 v0 = *(const float4*)src;
      const float4 v1 = *(const float4*)(src + 4);
      uint4 u;
      u.x = cvtpk(v0.x, v0.y);
      u.y = cvtpk(v0.z, v0.w);
      u.z = cvtpk(v1.x, v1.y);
      u.w = cvtpk(v1.z, v1.w);
      *(uint4*)(ximg + (size_t)idx * 16) = u;
    }
  } else {
    const int h = bx - 1024;
    const int k = t >> 1;
    const int chalf = t & 1;
    const float* wp = wqkv + (size_t)k * 1536 + (chalf ? (1024 + h * 64) : (512 + h * 64));
    const float4* wp4 = (const float4*)wp;
    const int c0 = chalf * 64;
    float4 wv[16];
    float sum = 0.f;
#pragma unroll
    for (int jj = 0; jj < 16; ++jj) {
      wv[jj] = wp4[jj];
      sum += wv[jj].x + wv[jj].y + wv[jj].z + wv[jj].w;
    }
    const float mean = sum * (1.f / 64.f);
#pragma unroll
    for (int jj = 0; jj < 16; ++jj) {
      const int c = c0 + jj * 4;
      const unsigned int cx0 = (unsigned int)((c + 0) & 7) << 4;
      const unsigned int cx1 = (unsigned int)((c + 1) & 7) << 4;
      const unsigned int cx2 = (unsigned int)((c + 2) & 7) << 4;
      const unsigned int cx3 = (unsigned int)((c + 3) & 7) << 4;
      *(unsigned short*)(wb + (c + 0) * 256 + (((unsigned)(2 * k)) ^ cx0)) = f2bf(wv[jj].x - mean);
      *(unsigned short*)(wb + (c + 1) * 256 + (((unsigned)(2 * k)) ^ cx1)) = f2bf(wv[jj].y - mean);
      *(unsigned short*)(wb + (c + 2) * 256 + (((unsigned)(2 * k)) ^ cx2)) = f2bf(wv[jj].z - mean);
      *(unsigned short*)(wb + (c + 3) * 256 + (((unsigned)(2 * k)) ^ cx3)) = f2bf(wv[jj].w - mean);
    }
    __syncthreads();
    const uint4* s4 = (const uint4*)(wb + t * 128);
    uint4* d4 = (uint4*)(wimg + (size_t)h * 32768 + t * 128);
#pragma unroll
    for (int i = 0; i < 8; ++i) d4[i] = s4[i];
  }
}

// ---------------------------------------------------------------------------
// K1 v2: pure gll staging + MFMA. Per (b,h,chunk of 256 rows), 4 tiles of 64,
// x double-buffered. 2 raw barriers per tile (lgkm after KT/VT write; vm at
// tile end for the prefetch). 80 KB LDS -> 2 blocks/CU.
// ---------------------------------------------------------------------------
__global__ __launch_bounds__(256) void kv_dots_v2(const unsigned char* __restrict__ ximg,
                                                  const unsigned char* __restrict__ wimg,
                                                  float* __restrict__ dots) {
  __shared__ __align__(16) unsigned char smem[81920];
  unsigned char* const XB0 = smem;           // 16 KB
  unsigned char* const XB1 = smem + 16384;   // 16 KB
  unsigned char* const WB = smem + 32768;    // 32 KB
  unsigned char* const KT = smem + 65536;    // 8 KB
  unsigned char* const VT = smem + 73728;    // 8 KB

  const int t = threadIdx.x;
  const int bx = blockIdx.x;
  const int h = bx >> 7;
  const int p = bx & 127;
  const int b = p >> 5;
  const int chunk = p & 31;

  const int wave = t >> 6;
  const int lane = t & 63;
  const int lb = lane & 15;
  const int kg = lane >> 4;
  const unsigned int lxor = (unsigned int)(lb & 7) << 4;

  const unsigned char* wsrc = wimg + (size_t)h * 32768;
  const unsigned char* xsrc = ximg + (size_t)(b * 128 + chunk * 4) * 16384;

#pragma unroll
  for (int i = 0; i < 8; ++i)
    gll16(wsrc + (wave * 8 + i) * 1024 + lane * 16, WB + (wave * 8 + i) * 1024);
#pragma unroll
  for (int i = 0; i < 4; ++i)
    gll16(xsrc + (wave * 4 + i) * 1024 + lane * 16, XB0 + (wave * 4 + i) * 1024);

  f32x4 dacc[4];
#pragma unroll
  for (int nt = 0; nt < 4; ++nt) dacc[nt] = (f32x4)0.f;

  BAR_VM();

  unsigned char* XBc = XB0;
  unsigned char* XBn = XB1;
  const int arow = wave * 16 + lb;

  for (int tile = 0; tile < 4; ++tile) {
    if (tile < 3) {
#pragma unroll
      for (int i = 0; i < 4; ++i)
        gll16(xsrc + (size_t)(tile + 1) * 16384 + (wave * 4 + i) * 1024 + lane * 16,
              XBn + (wave * 4 + i) * 1024);
    }

    // ---- kv = x @ W' via MFMA ----
    f32x4 acc[8];
#pragma unroll
    for (int ct = 0; ct < 8; ++ct) acc[ct] = (f32x4)0.f;
#pragma unroll
    for (int ks = 0; ks < 4; ++ks) {
      const unsigned int koff = (unsigned int)(ks * 64 + kg * 16);
      const short8 a = *(const short8*)(XBc + arow * 256 + (koff ^ lxor));
#pragma unroll
      for (int ct = 0; ct < 8; ++ct) {
        const short8 bf = *(const short8*)(WB + (ct * 16 + lb) * 256 + (koff ^ lxor));
        acc[ct] = __builtin_amdgcn_mfma_f32_16x16x32_bf16(a, bf, acc[ct], 0, 0, 0);
      }
    }

    // ---- variance (inputs centered via W'): kscale = s_k*s_v ----
    float kscale[4];
#pragma unroll
    for (int e = 0; e < 4; ++e) {
      float sk = acc[0][e] * acc[0][e] + acc[1][e] * acc[1][e] +
                 acc[2][e] * acc[2][e] + acc[3][e] * acc[3][e];
      float sv = acc[4][e] * acc[4][e] + acc[5][e] * acc[5][e] +
                 acc[6][e] * acc[6][e] + acc[7][e] * acc[7][e];
      sk += __shfl_xor(sk, 1); sv += __shfl_xor(sv, 1);
      sk += __shfl_xor(sk, 2); sv += __shfl_xor(sv, 2);
      sk += __shfl_xor(sk, 4); sv += __shfl_xor(sv, 4);
      sk += __shfl_xor(sk, 8); sv += __shfl_xor(sv, 8);
      kscale[e] = rsqrtf(sk * (1.f / 64.f) + 1e-5f) * rsqrtf(sv * (1.f / 64.f) + 1e-5f);
    }

    // ---- write kT (scaled) / vT (raw); prev dots reads fenced by last BAR_VM ----
    {
      const unsigned int rb2 = (unsigned int)(32 * wave + kg * 8);
#pragma unroll
      for (int ct = 0; ct < 4; ++ct) {
        uint2 w;
        w.x = cvtpk(acc[ct][0] * kscale[0], acc[ct][1] * kscale[1]);
        w.y = cvtpk(acc[ct][2] * kscale[2], acc[ct][3] * kscale[3]);
        *(uint2*)(KT + (ct * 16 + lb) * 128 + (rb2 ^ lxor)) = w;
      }
#pragma unroll
      for (int ct = 4; ct < 8; ++ct) {
        uint2 w;
        w.x = cvtpk(acc[ct][0], acc[ct][1]);
        w.y = cvtpk(acc[ct][2], acc[ct][3]);
        *(uint2*)(VT + ((ct - 4) * 16 + lb) * 128 + (rb2 ^ lxor)) = w;
      }
    }
    BAR_LGKM();

    // ---- dots += kT @ v ----
#pragma unroll
    for (int ks2 = 0; ks2 < 2; ++ks2) {
      const unsigned int koff = (unsigned int)(ks2 * 64 + kg * 16);
      const short8 a = *(const short8*)(KT + (wave * 16 + lb) * 128 + (koff ^ lxor));
#pragma unroll
      for (int nt = 0; nt < 4; ++nt) {
        const short8 bf = *(const short8*)(VT + (nt * 16 + lb) * 128 + (koff ^ lxor));
        dacc[nt] = __builtin_amdgcn_mfma_f32_16x16x32_bf16(a, bf, dacc[nt], 0, 0, 0);
      }
    }
    BAR_VM();

    unsigned char* tmp = XBc; XBc = XBn; XBn = tmp;
  }

  float* dp = dots + (size_t)(b * 8 + h) * 4096;
#pragma unroll
  for (int nt = 0; nt < 4; ++nt) {
#pragma unroll
    for (int reg = 0; reg < 4; ++reg) {
      const int d = 16 * wave + kg * 4 + reg;
      const int e = nt * 16 + lb;
      atomicAdd(&dp[d * 64 + e], dacc[nt][reg]);
    }
  }
}

// ---------------------------------------------------------------------------
// K2 (fused t + bigw), c-split. TR=1: store part transposed [j][c] for the
// coalesced bf16-image reduce; TR=0: legacy [c][j] layout (fallback path).
// ---------------------------------------------------------------------------
template <int TR>
__global__ __launch_bounds__(256) void tw_kernel(const float* __restrict__ wqkv,
                                                 const float* __restrict__ wout,
                                                 const float* __restrict__ dots,
                                                 float* __restrict__ part) {
  __shared__ __align__(16) float ds[64 * 66];
  __shared__ __align__(16) float wqT[64 * 36];
  __shared__ __align__(16) float Ts[32 * 66];
  __shared__ __align__(16) float wos[64 * 132];

  const int blk = blockIdx.x;
  const int bh = blk >> 2;
  const int cq = blk & 3;
  const int h = bh & 7;
  const int t = threadIdx.x;

  for (int i = t; i < 4096; i += 256)
    ds[(i >> 6) * 66 + (i & 63)] = dots[(size_t)bh * 4096 + i];

  for (int i = t; i < 2048; i += 256) {
    const int d = i >> 5;
    const int c = i & 31;
    wqT[d * 36 + c] = wqkv[(size_t)(cq * 32 + c) * 1536 + h * 64 + d];
  }

  for (int i = t; i < 2048; i += 256) {
    const int e = i >> 5;
    const int jj = (i & 31) * 4;
    *(float4*)&wos[e * 132 + jj] = *(const float4*)(wout + (size_t)(h * 64 + e) * 128 + jj);
  }
  __syncthreads();

  {
    const int c = t >> 3;
    const int e0 = (t & 7) * 8;
    float acc[8];
#pragma unroll
    for (int q = 0; q < 8; ++q) acc[q] = 0.f;
    for (int d = 0; d < 64; ++d) {
      const float wq = wqT[d * 36 + c];
      const float4 d0 = *(const float4*)&ds[d * 66 + e0];
      const float4 d1 = *(const float4*)&ds[d * 66 + e0 + 4];
      acc[0] += wq * d0.x; acc[1] += wq * d0.y; acc[2] += wq * d0.z; acc[3] += wq * d0.w;
      acc[4] += wq * d1.x; acc[5] += wq * d1.y; acc[6] += wq * d1.z; acc[7] += wq * d1.w;
    }
    *(float4*)&Ts[c * 66 + e0] = make_float4(acc[0], acc[1], acc[2], acc[3]);
    *(float4*)&Ts[c * 66 + e0 + 4] = make_float4(acc[4], acc[5], acc[6], acc[7]);
  }
  __syncthreads();

  {
    const int c = t >> 3;
    const int j0 = (t & 7) * 16;
    float acc[16];
#pragma unroll
    for (int q = 0; q < 16; ++q) acc[q] = 0.f;
    for (int e = 0; e < 64; ++e) {
      const float tv = Ts[c * 66 + e];
#pragma unroll
      for (int q = 0; q < 16; q += 4) {
        const float4 wv = *(const float4*)&wos[e * 132 + j0 + q];
        acc[q + 0] += tv * wv.x;
        acc[q + 1] += tv * wv.y;
        acc[q + 2] += tv * wv.z;
        acc[q + 3] += tv * wv.w;
      }
    }
    if (TR) {
      float* pp = part + (size_t)bh * 16384;
      const int cc = cq * 32 + c;
#pragma unroll
      for (int q = 0; q < 16; ++q) pp[(j0 + q) * 128 + cc] = acc[q];
    } else {
      float* pp = part + (size_t)bh * 16384 + (size_t)(cq * 32 + c) * 128 + j0;
#pragma unroll
      for (int q = 0; q < 16; q += 4)
        *(float4*)&pp[q] = make_float4(acc[q], acc[q + 1], acc[q + 2], acc[q + 3]);
    }
  }
}

// ---------------------------------------------------------------------------
// K2r v2: bigwimg (bf16, swizzled, per-b 32KB: byte = j*256 + ((2c)^((j&7)<<4)))
//         = (1/n) * sum_h part_T[b,h][j][c]
// ---------------------------------------------------------------------------
__global__ __launch_bounds__(256) void bigw_reduce_v2(const float* __restrict__ part,
                                                      unsigned char* __restrict__ bigwimg) {
  const int idx = blockIdx.x * 256 + threadIdx.x;  // 16B chunk, 0..8191
  const int b = idx >> 11;
  const int o = (idx & 2047) << 4;
  const int j = o >> 8;
  const int q0 = o & 255;
  const int c0 = (q0 ^ ((j & 7) << 4)) >> 1;
  float s[8];
#pragma unroll
  for (int i = 0; i < 8; ++i) s[i] = 0.f;
  const float* pb = part + (size_t)b * 8 * 16384 + j * 128 + c0;
#pragma unroll
  for (int hh = 0; hh < 8; ++hh) {
    const float4 p0 = *(const float4*)(pb + hh * 16384);
    const float4 p1 = *(const float4*)(pb + hh * 16384 + 4);
    s[0] += p0.x; s[1] += p0.y; s[2] += p0.z; s[3] += p0.w;
    s[4] += p1.x; s[5] += p1.y; s[6] += p1.z; s[7] += p1.w;
  }
  const float inv_n = 1.f / (float)NN;
  uint4 u;
  u.x = cvtpk(s[0] * inv_n, s[1] * inv_n);
  u.y = cvtpk(s[2] * inv_n, s[3] * inv_n);
  u.z = cvtpk(s[4] * inv_n, s[5] * inv_n);
  u.w = cvtpk(s[6] * inv_n, s[7] * inv_n);
  *(uint4*)(bigwimg + (size_t)idx * 16) = u;
}

// ---------------------------------------------------------------------------
// K3 v2: out = x @ BigW + bias, pure gll staging. 48 KB LDS, grid 512.
// ---------------------------------------------------------------------------
__global__ __launch_bounds__(256) void out_v2(const unsigned char* __restrict__ ximg,
                                              const unsigned char* __restrict__ bigwimg,
                                              const float* __restrict__ bout,
                                              float* __restrict__ out) {
  __shared__ __align__(16) unsigned char smem[49152];
  unsigned char* const XB = smem;
  unsigned char* const WJ = smem + 16384;

  const int t = threadIdx.x;
  const int bx = blockIdx.x;
  const int b = bx >> 7;
  const int tile = bx & 127;

  const int wave = t >> 6;
  const int lane = t & 63;
  const int lb = lane & 15;
  const int kg = lane >> 4;
  const unsigned int lxor = (unsigned int)(lb & 7) << 4;

  const unsigned char* wsrc = bigwimg + (size_t)b * 32768;
  const unsigned char* xsrc = ximg + (size_t)(b * 128 + tile) * 16384;

#pragma unroll
  for (int i = 0; i < 8; ++i)
    gll16(wsrc + (wave * 8 + i) * 1024 + lane * 16, WJ + (wave * 8 + i) * 1024);
#pragma unroll
  for (int i = 0; i < 4; ++i)
    gll16(xsrc + (wave * 4 + i) * 1024 + lane * 16, XB + (wave * 4 + i) * 1024);

  float bias[8];
#pragma unroll
  for (int ct = 0; ct < 8; ++ct) bias[ct] = bout[ct * 16 + lb];

  BAR_VM();

  f32x4 acc[8];
#pragma unroll
  for (int ct = 0; ct < 8; ++ct) acc[ct] = (f32x4)0.f;
  const int arow = wave * 16 + lb;
#pragma unroll
  for (int ks = 0; ks < 4; ++ks) {
    const unsigned int koff = (unsigned int)(ks * 64 + kg * 16);
    const short8 a = *(const short8*)(XB + arow * 256 + (koff ^ lxor));
#pragma unroll
    for (int ct = 0; ct < 8; ++ct) {
      const short8 bf = *(const short8*)(WJ + (ct * 16 + lb) * 256 + (koff ^ lxor));
      acc[ct] = __builtin_amdgcn_mfma_f32_16x16x32_bf16(a, bf, acc[ct], 0, 0, 0);
    }
  }

  float* op = out + (size_t)(b * NN + tile * 64 + 16 * wave + kg * 4) * DIM;
#pragma unroll
  for (int ct = 0; ct < 8; ++ct) {
#pragma unroll
    for (int reg = 0; reg < 4; ++reg) {
      op[reg * DIM + ct * 16 + lb] = acc[ct][reg] + bias[ct];
    }
  }
}

// ===========================================================================
// Fallback path (R6, known-good) used if ws_size is too small for the images.
// ===========================================================================
__global__ __launch_bounds__(256) void kv_dots_fb(const float* __restrict__ x,
                                                  const float* __restrict__ wqkv,
                                                  float* __restrict__ dots) {
  __shared__ __align__(16) unsigned char smem[49152];
  unsigned char* const XB = smem;
  unsigned char* const KT = smem;
  unsigned char* const VT = smem + 8192;
  unsigned char* const WB = smem + 16384;

  const int t = threadIdx.x;
  const int bx = blockIdx.x;
  const int h = bx >> 7;
  const int p = bx & 127;
  const int b = p >> 5;
  const int chunk = p & 31;
  const int row0 = chunk * 256;

  const int wave = t >> 6;
  const int lane = t & 63;
  const int lb = lane & 15;
  const int kg = lane >> 4;
  const unsigned int lxor = (unsigned int)(lb & 7) << 4;

  {
    const int k = t >> 1;
    const int chalf = t & 1;
    const float* wp = wqkv + (size_t)k * 1536 + (chalf ? (1024 + h * 64) : (512 + h * 64));
    const float4* wp4 = (const float4*)wp;
    const int c0 = chalf * 64;
    float4 wv[16];
    float sum = 0.f;
#pragma unroll
    for (int jj = 0; jj < 16; ++jj) {
      wv[jj] = wp4[jj];
      sum += wv[jj].x + wv[jj].y + wv[jj].z + wv[jj].w;
    }
    const float mean = sum * (1.f / 64.f);
#pragma unroll
    for (int jj = 0; jj < 16; ++jj) {
      const int c = c0 + jj * 4;
      const unsigned int cx0 = (unsigned int)((c + 0) & 7) << 4;
      const unsigned int cx1 = (unsigned int)((c + 1) & 7) << 4;
      const unsigned int cx2 = (unsigned int)((c + 2) & 7) << 4;
      const unsigned int cx3 = (unsigned int)((c + 3) & 7) << 4;
      *(unsigned short*)(WB + (c + 0) * 256 + (((unsigned)(2 * k)) ^ cx0)) = f2bf(wv[jj].x - mean);
      *(unsigned short*)(WB + (c + 1) * 256 + (((unsigned)(2 * k)) ^ cx1)) = f2bf(wv[jj].y - mean);
      *(unsigned short*)(WB + (c + 2) * 256 + (((unsigned)(2 * k)) ^ cx2)) = f2bf(wv[jj].z - mean);
      *(unsigned short*)(WB + (c + 3) * 256 + (((unsigned)(2 * k)) ^ cx3)) = f2bf(wv[jj].w - mean);
    }
  }

  f32x4 dacc[4];
#pragma unroll
  for (int nt = 0; nt < 4; ++nt) dacc[nt] = (f32x4)0.f;

  __syncthreads();

  for (int tile = 0; tile < 4; ++tile) {
    const int rowbase = row0 + tile * 64;
    __syncthreads();
    {
      const int r = t >> 2;
      const int cb = (t & 3) * 32;
      const float4* gp4 = (const float4*)(x + (size_t)(b * NN + rowbase + r) * DIM + cb);
      const unsigned int rxor = (unsigned int)(r & 7) << 4;
#pragma unroll
      for (int jj = 0; jj < 4; ++jj) {
        const float4 v0 = gp4[2 * jj];
        const float4 v1 = gp4[2 * jj + 1];
        uint4 u;
        u.x = cvtpk(v0.x, v0.y);
        u.y = cvtpk(v0.z, v0.w);
        u.z = cvtpk(v1.x, v1.y);
        u.w = cvtpk(v1.z, v1.w);
        *(uint4*)(XB + r * 256 + (((unsigned)(2 * cb + 16 * jj)) ^ rxor)) = u;
      }
    }
    __syncthreads();

    f32x4 acc[8];
#pragma unroll
    for (int ct = 0; ct < 8; ++ct) acc[ct] = (f32x4)0.f;
    const int arow = wave * 16 + lb;
#pragma unroll
    for (int ks = 0; ks < 4; ++ks) {
      const unsigned int koff = (unsigned int)(ks * 64 + kg * 16);
      const short8 a = *(const short8*)(XB + arow * 256 + (koff ^ lxor));
#pragma unroll
      for (int ct = 0; ct < 8; ++ct) {
        const short8 bf = *(const short8*)(WB + (ct * 16 + lb) * 256 + (koff ^ lxor));
        acc[ct] = __builtin_amdgcn_mfma_f32_16x16x32_bf16(a, bf, acc[ct], 0, 0, 0);
      }
    }

    float kscale[4];
#pragma unroll
    for (int e = 0; e < 4; ++e) {
      float sk = acc[0][e] * acc[0][e] + acc[1][e] * acc[1][e] +
                 acc[2][e] * acc[2][e] + acc[3][e] * acc[3][e];
      float sv = acc[4][e] * acc[4][e] + acc[5][e] * acc[5][e] +
                 acc[6][e] * acc[6][e] + acc[7][e] * acc[7][e];
      sk += __shfl_xor(sk, 1); sv += __shfl_xor(sv, 1);
      sk += __shfl_xor(sk, 2); sv += __shfl_xor(sv, 2);
      sk += __shfl_xor(sk, 4); sv += __shfl_xor(sv, 4);
      sk += __shfl_xor(sk, 8); sv += __shfl_xor(sv, 8);
      kscale[e] = rsqrtf(sk * (1.f / 64.f) + 1e-5f) * rsqrtf(sv * (1.f / 64.f) + 1e-5f);
    }

    __syncthreads();
    {
      const unsigned int rb2 = (unsigned int)(32 * wave + kg * 8);
#pragma unroll
      for (int ct = 0; ct < 4; ++ct) {
        uint2 w;
        w.x = cvtpk(acc[ct][0] * kscale[0], acc[ct][1] * kscale[1]);
        w.y = cvtpk(acc[ct][2] * kscale[2], acc[ct][3] * kscale[3]);
        *(uint2*)(KT + (ct * 16 + lb) * 128 + (rb2 ^ lxor)) = w;
      }
#pragma unroll
      for (int ct = 4; ct < 8; ++ct) {
        uint2 w;
        w.x = cvtpk(acc[ct][0], acc[ct][1]);
        w.y = cvtpk(acc[ct][2], acc[ct][3]);
        *(uint2*)(VT + ((ct - 4) * 16 + lb) * 128 + (rb2 ^ lxor)) = w;
      }
    }
    __syncthreads();

#pragma unroll
    for (int ks2 = 0; ks2 < 2; ++ks2) {
      const unsigned int koff = (unsigned int)(ks2 * 64 + kg * 16);
      const short8 a = *(const short8*)(KT + (wave * 16 + lb) * 128 + (koff ^ lxor));
#pragma unroll
      for (int nt = 0; nt < 4; ++nt) {
        const short8 bf = *(const short8*)(VT + (nt * 16 + lb) * 128 + (koff ^ lxor));
        dacc[nt] = __builtin_amdgcn_mfma_f32_16x16x32_bf16(a, bf, dacc[nt], 0, 0, 0);
      }
    }
  }

  float* dp = dots + (size_t)(b * 8 + h) * 4096;
#pragma unroll
  for (int nt = 0; nt < 4; ++nt) {
#pragma unroll
    for (int reg = 0; reg < 4; ++reg) {
      const int d = 16 * wave + kg * 4 + reg;
      const int e = nt * 16 + lb;
      atomicAdd(&dp[d * 64 + e], dacc[nt][reg]);
    }
  }
}

__global__ __launch_bounds__(256) void bigw_reduce_fb(const float* __restrict__ part,
                                                      float* __restrict__ bigw) {
  const int i = blockIdx.x * 256 + threadIdx.x;
  const int b = i >> 14;
  const int cj = i & 16383;
  const float* pp = part + (size_t)b * 8 * 16384 + cj;
  float s = 0.f;
#pragma unroll
  for (int h = 0; h < 8; ++h) s += pp[h * 16384];
  bigw[i] = s * (1.f / (float)NN);
}

__global__ __launch_bounds__(256) void out_fb(const float* __restrict__ x,
                                              const float* __restrict__ bigw,
                                              const float* __restrict__ bout,
                                              float* __restrict__ out) {
  __shared__ __align__(16) unsigned char smem[49152];
  unsigned char* const XB = smem;
  unsigned char* const WB = smem + 16384;

  const int t = threadIdx.x;
  const int bx = blockIdx.x;
  const int b = bx >> 7;
  const int rowbase = (bx & 127) * 64;

  const int wave = t >> 6;
  const int lane = t & 63;
  const int lb = lane & 15;
  const int kg = lane >> 4;
  const unsigned int lxor = (unsigned int)(lb & 7) << 4;

  {
    const int c = t >> 1;
    const int jhalf = t & 1;
    const float4* wp4 = (const float4*)(bigw + (size_t)b * 16384 + (size_t)c * 128 + jhalf * 64);
    const int j0 = jhalf * 64;
#pragma unroll
    for (int q = 0; q < 16; ++q) {
      const float4 v = wp4[q];
      const int j = j0 + q * 4;
      const unsigned int jx0 = (unsigned int)((j + 0) & 7) << 4;
      const unsigned int jx1 = (unsigned int)((j + 1) & 7) << 4;
      const unsigned int jx2 = (unsigned int)((j + 2) & 7) << 4;
      const unsigned int jx3 = (unsigned int)((j + 3) & 7) << 4;
      *(unsigned short*)(WB + (j + 0) * 256 + (((unsigned)(2 * c)) ^ jx0)) = f2bf(v.x);
      *(unsigned short*)(WB + (j + 1) * 256 + (((unsigned)(2 * c)) ^ jx1)) = f2bf(v.y);
      *(unsigned short*)(WB + (j + 2) * 256 + (((unsigned)(2 * c)) ^ jx2)) = f2bf(v.z);
      *(unsigned short*)(WB + (j + 3) * 256 + (((unsigned)(2 * c)) ^ jx3)) = f2bf(v.w);
    }
  }

  float bias[8];
#pragma unroll
  for (int ct = 0; ct < 8; ++ct) bias[ct] = bout[ct * 16 + lb];

  {
    const int r = t >> 2;
    const int cb = (t & 3) * 32;
    const float4* gp4 = (const float4*)(x + (size_t)(b * NN + rowbase + r) * DIM + cb);
    const unsigned int rxor = (unsigned int)(r & 7) << 4;
#pragma unroll
    for (int jj = 0; jj < 4; ++jj) {
      const float4 v0 = gp4[2 * jj];
      const float4 v1 = gp4[2 * jj + 1];
      uint4 u;
      u.x = cvtpk(v0.x, v0.y);
      u.y = cvtpk(v0.z, v0.w);
      u.z = cvtpk(v1.x, v1.y);
      u.w = cvtpk(v1.z, v1.w);
      *(uint4*)(XB + r * 256 + (((unsigned)(2 * cb + 16 * jj)) ^ rxor)) = u;
    }
  }
  __syncthreads();

  f32x4 acc[8];
#pragma unroll
  for (int ct = 0; ct < 8; ++ct) acc[ct] = (f32x4)0.f;
  const int arow = wave * 16 + lb;
#pragma unroll
  for (int ks = 0; ks < 4; ++ks) {
    const unsigned int koff = (unsigned int)(ks * 64 + kg * 16);
    const short8 a = *(const short8*)(XB + arow * 256 + (koff ^ lxor));
#pragma unroll
    for (int ct = 0; ct < 8; ++ct) {
      const short8 bf = *(const short8*)(WB + (ct * 16 + lb) * 256 + (koff ^ lxor));
      acc[ct] = __builtin_amdgcn_mfma_f32_16x16x32_bf16(a, bf, acc[ct], 0, 0, 0);
    }
  }

  float* op = out + (size_t)(b * NN + rowbase + 16 * wave + kg * 4) * DIM;
#pragma unroll
  for (int ct = 0; ct < 8; ++ct) {
#pragma unroll
    for (int reg = 0; reg < 4; ++reg) {
      op[reg * DIM + ct * 16 + lb] = acc[ct][reg] + bias[ct];
    }
  }
}

extern "C" void kernel_launch(void* const* d_in, const int* in_sizes, int n_in,
                              void* d_out, int out_size, void* d_ws, size_t ws_size,
                              hipStream_t stream) {
  (void)in_sizes; (void)n_in; (void)out_size;
  const float* x = (const float*)d_in[0];
  const float* wqkv = (const float*)d_in[1];
  const float* wout = (const float*)d_in[2];
  const float* bout = (const float*)d_in[3];
  float* out = (float*)d_out;

  const size_t NEED = 8388608ull + 262144ull + 131072ull + 524288ull + 2097152ull;
  if (ws_size >= NEED) {
    unsigned char* ximg = (unsigned char*)d_ws;            // 8 MB
    unsigned char* wimg = ximg + 8388608;                  // 256 KB
    unsigned char* bigwimg = wimg + 262144;                // 128 KB
    float* dots = (float*)(bigwimg + 131072);              // 512 KB
    float* part = dots + 131072;                           // 2 MB

    hipMemsetAsync(dots, 0, 131072 * sizeof(float), stream);
    hipLaunchKernelGGL(prep_kernel, dim3(1032), dim3(256), 0, stream, x, wqkv, ximg, wimg);
    hipLaunchKernelGGL(kv_dots_v2, dim3(1024), dim3(256), 0, stream, ximg, wimg, dots);
    hipLaunchKernelGGL((tw_kernel<1>), dim3(128), dim3(256), 0, stream, wqkv, wout, dots, part);
    hipLaunchKernelGGL(bigw_reduce_v2, dim3(32), dim3(256), 0, stream, part, bigwimg);
    hipLaunchKernelGGL(out_v2, dim3(512), dim3(256), 0, stream, ximg, bigwimg, bout, out);
  } else {
    float* dots = (float*)d_ws;
    float* part = dots + 131072;
    float* bigw = part + 524288;
    hipMemsetAsync(dots, 0, 131072 * sizeof(float), stream);
    hipLaunchKernelGGL(kv_dots_fb, dim3(1024), dim3(256), 0, stream, x, wqkv, dots);
    hipLaunchKernelGGL((tw_kernel<0>), dim3(128), dim3(256), 0, stream, wqkv, wout, dots, part);
    hipLaunchKernelGGL(bigw_reduce_fb, dim3(256), dim3(256), 0, stream, part, bigw);
    hipLaunchKernelGGL(out_fb, dim3(512), dim3(256), 0, stream, x, bigw, bout, out);
  }
}

// Round 8
// 70.564 us; speedup vs baseline: 8.5785x; 1.0674x over previous
//
#include <hip/hip_runtime.h>

#define NN 8192
#define DIM 128

typedef short short8 __attribute__((ext_vector_type(8)));
typedef float f32x4 __attribute__((ext_vector_type(4)));

__device__ __forceinline__ unsigned short f2bf(float f) {
  unsigned int u = __float_as_uint(f);
  u = (u + 0x7FFFu + ((u >> 16) & 1u)) >> 16;
  return (unsigned short)u;
}
__device__ __forceinline__ unsigned int cvtpk(float a, float b) {
  unsigned int r;
  asm("v_cvt_pk_bf16_f32 %0, %1, %2" : "=v"(r) : "v"(a), "v"(b));
  return r;
}
__device__ __forceinline__ void gll16(const void* gsrc, void* ldst) {
  __builtin_amdgcn_global_load_lds(
      (const __attribute__((address_space(1))) unsigned int*)gsrc,
      (__attribute__((address_space(3))) unsigned int*)ldst, 16, 0, 0);
}
#define BAR_LGKM()                                          \
  do {                                                      \
    asm volatile("s_waitcnt lgkmcnt(0)" ::: "memory");      \
    __builtin_amdgcn_sched_barrier(0);                      \
    __builtin_amdgcn_s_barrier();                           \
    __builtin_amdgcn_sched_barrier(0);                      \
  } while (0)
#define BAR_VM()                                            \
  do {                                                      \
    asm volatile("s_waitcnt vmcnt(0)" ::: "memory");        \
    __builtin_amdgcn_sched_barrier(0);                      \
    __builtin_amdgcn_s_barrier();                           \
    __builtin_amdgcn_sched_barrier(0);                      \
  } while (0)

// ---------------------------------------------------------------------------
// PREP: blocks 0..1023:  x -> bf16 swizzled tile images (8 MB)
//       blocks 1024..1031: per-head centered W_kv^T bf16 swizzled image
//       blocks 1032..1039: zero `dots` (replaces hipMemsetAsync: the rocclr
//                          fill kernel measured ~44 us for 512 KB!)
// ---------------------------------------------------------------------------
__global__ __launch_bounds__(256) void prep_kernel(const float* __restrict__ x,
                                                   const float* __restrict__ wqkv,
                                                   unsigned char* __restrict__ ximg,
                                                   unsigned char* __restrict__ wimg,
                                                   float* __restrict__ dots) {
  __shared__ __align__(16) unsigned char wb[32768];
  const int t = threadIdx.x;
  const int bx = blockIdx.x;
  if (bx < 1024) {
#pragma unroll
    for (int rep = 0; rep < 2; ++rep) {
      const int idx = bx * 512 + rep * 256 + t;  // 16B chunk index, 0..524287
      const int bt = idx >> 10;                  // b*128 + tile
      const int o = (idx & 1023) << 4;           // byte in 16KB image
      const int r = o >> 8;
      const int q0 = o & 255;
      const int c0 = (q0 ^ ((r & 7) << 4)) >> 1;
      const float* src = x + ((size_t)(bt >> 7) * NN + (size_t)(bt & 127) * 64 + r) * DIM + c0;
      const float4 v0 = *(const float4*)src;
      const float4 v1 = *(const float4*)(src + 4);
      uint4 u;
      u.x = cvtpk(v0.x, v0.y);
      u.y = cvtpk(v0.z, v0.w);
      u.z = cvtpk(v1.x, v1.y);
      u.w = cvtpk(v1.z, v1.w);
      *(uint4*)(ximg + (size_t)idx * 16) = u;
    }
  } else if (bx < 1032) {
    const int h = bx - 1024;
    const int k = t >> 1;
    const int chalf = t & 1;
    const float* wp = wqkv + (size_t)k * 1536 + (chalf ? (1024 + h * 64) : (512 + h * 64));
    const float4* wp4 = (const float4*)wp;
    const int c0 = chalf * 64;
    float4 wv[16];
    float sum = 0.f;
#pragma unroll
    for (int jj = 0; jj < 16; ++jj) {
      wv[jj] = wp4[jj];
      sum += wv[jj].x + wv[jj].y + wv[jj].z + wv[jj].w;
    }
    const float mean = sum * (1.f / 64.f);
#pragma unroll
    for (int jj = 0; jj < 16; ++jj) {
      const int c = c0 + jj * 4;
      const unsigned int cx0 = (unsigned int)((c + 0) & 7) << 4;
      const unsigned int cx1 = (unsigned int)((c + 1) & 7) << 4;
      const unsigned int cx2 = (unsigned int)((c + 2) & 7) << 4;
      const unsigned int cx3 = (unsigned int)((c + 3) & 7) << 4;
      *(unsigned short*)(wb + (c + 0) * 256 + (((unsigned)(2 * k)) ^ cx0)) = f2bf(wv[jj].x - mean);
      *(unsigned short*)(wb + (c + 1) * 256 + (((unsigned)(2 * k)) ^ cx1)) = f2bf(wv[jj].y - mean);
      *(unsigned short*)(wb + (c + 2) * 256 + (((unsigned)(2 * k)) ^ cx2)) = f2bf(wv[jj].z - mean);
      *(unsigned short*)(wb + (c + 3) * 256 + (((unsigned)(2 * k)) ^ cx3)) = f2bf(wv[jj].w - mean);
    }
    __syncthreads();
    const uint4* s4 = (const uint4*)(wb + t * 128);
    uint4* d4 = (uint4*)(wimg + (size_t)h * 32768 + t * 128);
#pragma unroll
    for (int i = 0; i < 8; ++i) d4[i] = s4[i];
  } else {
    // zero dots: 131072 floats over 8 blocks = 4096 float4 per block
    const int zb = bx - 1032;
    float4* dz = (float4*)dots + (size_t)zb * 4096 + t;
    const float4 z = make_float4(0.f, 0.f, 0.f, 0.f);
#pragma unroll
    for (int i = 0; i < 16; ++i) dz[i * 256] = z;
  }
}

// ---------------------------------------------------------------------------
// K1 v2: pure gll staging + MFMA. Per (b,h,chunk of 256 rows), 4 tiles of 64,
// x double-buffered. 2 raw barriers per tile. 80 KB LDS -> 2 blocks/CU.
// ---------------------------------------------------------------------------
__global__ __launch_bounds__(256) void kv_dots_v2(const unsigned char* __restrict__ ximg,
                                                  const unsigned char* __restrict__ wimg,
                                                  float* __restrict__ dots) {
  __shared__ __align__(16) unsigned char smem[81920];
  unsigned char* const XB0 = smem;           // 16 KB
  unsigned char* const XB1 = smem + 16384;   // 16 KB
  unsigned char* const WB = smem + 32768;    // 32 KB
  unsigned char* const KT = smem + 65536;    // 8 KB
  unsigned char* const VT = smem + 73728;    // 8 KB

  const int t = threadIdx.x;
  const int bx = blockIdx.x;
  const int h = bx >> 7;
  const int p = bx & 127;
  const int b = p >> 5;
  const int chunk = p & 31;

  const int wave = t >> 6;
  const int lane = t & 63;
  const int lb = lane & 15;
  const int kg = lane >> 4;
  const unsigned int lxor = (unsigned int)(lb & 7) << 4;

  const unsigned char* wsrc = wimg + (size_t)h * 32768;
  const unsigned char* xsrc = ximg + (size_t)(b * 128 + chunk * 4) * 16384;

#pragma unroll
  for (int i = 0; i < 8; ++i)
    gll16(wsrc + (wave * 8 + i) * 1024 + lane * 16, WB + (wave * 8 + i) * 1024);
#pragma unroll
  for (int i = 0; i < 4; ++i)
    gll16(xsrc + (wave * 4 + i) * 1024 + lane * 16, XB0 + (wave * 4 + i) * 1024);

  f32x4 dacc[4];
#pragma unroll
  for (int nt = 0; nt < 4; ++nt) dacc[nt] = (f32x4)0.f;

  BAR_VM();

  unsigned char* XBc = XB0;
  unsigned char* XBn = XB1;
  const int arow = wave * 16 + lb;

  for (int tile = 0; tile < 4; ++tile) {
    if (tile < 3) {
#pragma unroll
      for (int i = 0; i < 4; ++i)
        gll16(xsrc + (size_t)(tile + 1) * 16384 + (wave * 4 + i) * 1024 + lane * 16,
              XBn + (wave * 4 + i) * 1024);
    }

    // ---- kv = x @ W' via MFMA ----
    f32x4 acc[8];
#pragma unroll
    for (int ct = 0; ct < 8; ++ct) acc[ct] = (f32x4)0.f;
#pragma unroll
    for (int ks = 0; ks < 4; ++ks) {
      const unsigned int koff = (unsigned int)(ks * 64 + kg * 16);
      const short8 a = *(const short8*)(XBc + arow * 256 + (koff ^ lxor));
#pragma unroll
      for (int ct = 0; ct < 8; ++ct) {
        const short8 bf = *(const short8*)(WB + (ct * 16 + lb) * 256 + (koff ^ lxor));
        acc[ct] = __builtin_amdgcn_mfma_f32_16x16x32_bf16(a, bf, acc[ct], 0, 0, 0);
      }
    }

    // ---- variance (inputs centered via W'): kscale = s_k*s_v ----
    float kscale[4];
#pragma unroll
    for (int e = 0; e < 4; ++e) {
      float sk = acc[0][e] * acc[0][e] + acc[1][e] * acc[1][e] +
                 acc[2][e] * acc[2][e] + acc[3][e] * acc[3][e];
      float sv = acc[4][e] * acc[4][e] + acc[5][e] * acc[5][e] +
                 acc[6][e] * acc[6][e] + acc[7][e] * acc[7][e];
      sk += __shfl_xor(sk, 1); sv += __shfl_xor(sv, 1);
      sk += __shfl_xor(sk, 2); sv += __shfl_xor(sv, 2);
      sk += __shfl_xor(sk, 4); sv += __shfl_xor(sv, 4);
      sk += __shfl_xor(sk, 8); sv += __shfl_xor(sv, 8);
      kscale[e] = rsqrtf(sk * (1.f / 64.f) + 1e-5f) * rsqrtf(sv * (1.f / 64.f) + 1e-5f);
    }

    // ---- write kT (scaled) / vT (raw) ----
    {
      const unsigned int rb2 = (unsigned int)(32 * wave + kg * 8);
#pragma unroll
      for (int ct = 0; ct < 4; ++ct) {
        uint2 w;
        w.x = cvtpk(acc[ct][0] * kscale[0], acc[ct][1] * kscale[1]);
        w.y = cvtpk(acc[ct][2] * kscale[2], acc[ct][3] * kscale[3]);
        *(uint2*)(KT + (ct * 16 + lb) * 128 + (rb2 ^ lxor)) = w;
      }
#pragma unroll
      for (int ct = 4; ct < 8; ++ct) {
        uint2 w;
        w.x = cvtpk(acc[ct][0], acc[ct][1]);
        w.y = cvtpk(acc[ct][2], acc[ct][3]);
        *(uint2*)(VT + ((ct - 4) * 16 + lb) * 128 + (rb2 ^ lxor)) = w;
      }
    }
    BAR_LGKM();

    // ---- dots += kT @ v ----
#pragma unroll
    for (int ks2 = 0; ks2 < 2; ++ks2) {
      const unsigned int koff = (unsigned int)(ks2 * 64 + kg * 16);
      const short8 a = *(const short8*)(KT + (wave * 16 + lb) * 128 + (koff ^ lxor));
#pragma unroll
      for (int nt = 0; nt < 4; ++nt) {
        const short8 bf = *(const short8*)(VT + (nt * 16 + lb) * 128 + (koff ^ lxor));
        dacc[nt] = __builtin_amdgcn_mfma_f32_16x16x32_bf16(a, bf, dacc[nt], 0, 0, 0);
      }
    }
    BAR_VM();

    unsigned char* tmp = XBc; XBc = XBn; XBn = tmp;
  }

  float* dp = dots + (size_t)(b * 8 + h) * 4096;
#pragma unroll
  for (int nt = 0; nt < 4; ++nt) {
#pragma unroll
    for (int reg = 0; reg < 4; ++reg) {
      const int d = 16 * wave + kg * 4 + reg;
      const int e = nt * 16 + lb;
      atomicAdd(&dp[d * 64 + e], dacc[nt][reg]);
    }
  }
}

// ---------------------------------------------------------------------------
// K2 (fused t + bigw), c-split. TR=1: store part transposed [j][c].
// ---------------------------------------------------------------------------
template <int TR>
__global__ __launch_bounds__(256) void tw_kernel(const float* __restrict__ wqkv,
                                                 const float* __restrict__ wout,
                                                 const float* __restrict__ dots,
                                                 float* __restrict__ part) {
  __shared__ __align__(16) float ds[64 * 66];
  __shared__ __align__(16) float wqT[64 * 36];
  __shared__ __align__(16) float Ts[32 * 66];
  __shared__ __align__(16) float wos[64 * 132];

  const int blk = blockIdx.x;
  const int bh = blk >> 2;
  const int cq = blk & 3;
  const int h = bh & 7;
  const int t = threadIdx.x;

  for (int i = t; i < 4096; i += 256)
    ds[(i >> 6) * 66 + (i & 63)] = dots[(size_t)bh * 4096 + i];

  for (int i = t; i < 2048; i += 256) {
    const int d = i >> 5;
    const int c = i & 31;
    wqT[d * 36 + c] = wqkv[(size_t)(cq * 32 + c) * 1536 + h * 64 + d];
  }

  for (int i = t; i < 2048; i += 256) {
    const int e = i >> 5;
    const int jj = (i & 31) * 4;
    *(float4*)&wos[e * 132 + jj] = *(const float4*)(wout + (size_t)(h * 64 + e) * 128 + jj);
  }
  __syncthreads();

  {
    const int c = t >> 3;
    const int e0 = (t & 7) * 8;
    float acc[8];
#pragma unroll
    for (int q = 0; q < 8; ++q) acc[q] = 0.f;
    for (int d = 0; d < 64; ++d) {
      const float wq = wqT[d * 36 + c];
      const float4 d0 = *(const float4*)&ds[d * 66 + e0];
      const float4 d1 = *(const float4*)&ds[d * 66 + e0 + 4];
      acc[0] += wq * d0.x; acc[1] += wq * d0.y; acc[2] += wq * d0.z; acc[3] += wq * d0.w;
      acc[4] += wq * d1.x; acc[5] += wq * d1.y; acc[6] += wq * d1.z; acc[7] += wq * d1.w;
    }
    *(float4*)&Ts[c * 66 + e0] = make_float4(acc[0], acc[1], acc[2], acc[3]);
    *(float4*)&Ts[c * 66 + e0 + 4] = make_float4(acc[4], acc[5], acc[6], acc[7]);
  }
  __syncthreads();

  {
    const int c = t >> 3;
    const int j0 = (t & 7) * 16;
    float acc[16];
#pragma unroll
    for (int q = 0; q < 16; ++q) acc[q] = 0.f;
    for (int e = 0; e < 64; ++e) {
      const float tv = Ts[c * 66 + e];
#pragma unroll
      for (int q = 0; q < 16; q += 4) {
        const float4 wv = *(const float4*)&wos[e * 132 + j0 + q];
        acc[q + 0] += tv * wv.x;
        acc[q + 1] += tv * wv.y;
        acc[q + 2] += tv * wv.z;
        acc[q + 3] += tv * wv.w;
      }
    }
    if (TR) {
      float* pp = part + (size_t)bh * 16384;
      const int cc = cq * 32 + c;
#pragma unroll
      for (int q = 0; q < 16; ++q) pp[(j0 + q) * 128 + cc] = acc[q];
    } else {
      float* pp = part + (size_t)bh * 16384 + (size_t)(cq * 32 + c) * 128 + j0;
#pragma unroll
      for (int q = 0; q < 16; q += 4)
        *(float4*)&pp[q] = make_float4(acc[q], acc[q + 1], acc[q + 2], acc[q + 3]);
    }
  }
}

// ---------------------------------------------------------------------------
// K2r v2: bigwimg (bf16, swizzled) = (1/n) * sum_h part_T[b,h][j][c]
// ---------------------------------------------------------------------------
__global__ __launch_bounds__(256) void bigw_reduce_v2(const float* __restrict__ part,
                                                      unsigned char* __restrict__ bigwimg) {
  const int idx = blockIdx.x * 256 + threadIdx.x;  // 16B chunk, 0..8191
  const int b = idx >> 11;
  const int o = (idx & 2047) << 4;
  const int j = o >> 8;
  const int q0 = o & 255;
  const int c0 = (q0 ^ ((j & 7) << 4)) >> 1;
  float s[8];
#pragma unroll
  for (int i = 0; i < 8; ++i) s[i] = 0.f;
  const float* pb = part + (size_t)b * 8 * 16384 + j * 128 + c0;
#pragma unroll
  for (int hh = 0; hh < 8; ++hh) {
    const float4 p0 = *(const float4*)(pb + hh * 16384);
    const float4 p1 = *(const float4*)(pb + hh * 16384 + 4);
    s[0] += p0.x; s[1] += p0.y; s[2] += p0.z; s[3] += p0.w;
    s[4] += p1.x; s[5] += p1.y; s[6] += p1.z; s[7] += p1.w;
  }
  const float inv_n = 1.f / (float)NN;
  uint4 u;
  u.x = cvtpk(s[0] * inv_n, s[1] * inv_n);
  u.y = cvtpk(s[2] * inv_n, s[3] * inv_n);
  u.z = cvtpk(s[4] * inv_n, s[5] * inv_n);
  u.w = cvtpk(s[6] * inv_n, s[7] * inv_n);
  *(uint4*)(bigwimg + (size_t)idx * 16) = u;
}

// ---------------------------------------------------------------------------
// K3 v2: out = x @ BigW + bias, pure gll staging. 48 KB LDS, grid 512.
// ---------------------------------------------------------------------------
__global__ __launch_bounds__(256) void out_v2(const unsigned char* __restrict__ ximg,
                                              const unsigned char* __restrict__ bigwimg,
                                              const float* __restrict__ bout,
                                              float* __restrict__ out) {
  __shared__ __align__(16) unsigned char smem[49152];
  unsigned char* const XB = smem;
  unsigned char* const WJ = smem + 16384;

  const int t = threadIdx.x;
  const int bx = blockIdx.x;
  const int b = bx >> 7;
  const int tile = bx & 127;

  const int wave = t >> 6;
  const int lane = t & 63;
  const int lb = lane & 15;
  const int kg = lane >> 4;
  const unsigned int lxor = (unsigned int)(lb & 7) << 4;

  const unsigned char* wsrc = bigwimg + (size_t)b * 32768;
  const unsigned char* xsrc = ximg + (size_t)(b * 128 + tile) * 16384;

#pragma unroll
  for (int i = 0; i < 8; ++i)
    gll16(wsrc + (wave * 8 + i) * 1024 + lane * 16, WJ + (wave * 8 + i) * 1024);
#pragma unroll
  for (int i = 0; i < 4; ++i)
    gll16(xsrc + (wave * 4 + i) * 1024 + lane * 16, XB + (wave * 4 + i) * 1024);

  float bias[8];
#pragma unroll
  for (int ct = 0; ct < 8; ++ct) bias[ct] = bout[ct * 16 + lb];

  BAR_VM();

  f32x4 acc[8];
#pragma unroll
  for (int ct = 0; ct < 8; ++ct) acc[ct] = (f32x4)0.f;
  const int arow = wave * 16 + lb;
#pragma unroll
  for (int ks = 0; ks < 4; ++ks) {
    const unsigned int koff = (unsigned int)(ks * 64 + kg * 16);
    const short8 a = *(const short8*)(XB + arow * 256 + (koff ^ lxor));
#pragma unroll
    for (int ct = 0; ct < 8; ++ct) {
      const short8 bf = *(const short8*)(WJ + (ct * 16 + lb) * 256 + (koff ^ lxor));
      acc[ct] = __builtin_amdgcn_mfma_f32_16x16x32_bf16(a, bf, acc[ct], 0, 0, 0);
    }
  }

  float* op = out + (size_t)(b * NN + tile * 64 + 16 * wave + kg * 4) * DIM;
#pragma unroll
  for (int ct = 0; ct < 8; ++ct) {
#pragma unroll
    for (int reg = 0; reg < 4; ++reg) {
      op[reg * DIM + ct * 16 + lb] = acc[ct][reg] + bias[ct];
    }
  }
}

// ===========================================================================
// Fallback path (R6, known-good) used if ws_size is too small for the images.
// ===========================================================================
__global__ __launch_bounds__(256) void zero_dots_fb(float* __restrict__ dots) {
  float4* dz = (float4*)dots + (size_t)blockIdx.x * 4096 + threadIdx.x;
  const float4 z = make_float4(0.f, 0.f, 0.f, 0.f);
#pragma unroll
  for (int i = 0; i < 16; ++i) dz[i * 256] = z;
}

__global__ __launch_bounds__(256) void kv_dots_fb(const float* __restrict__ x,
                                                  const float* __restrict__ wqkv,
                                                  float* __restrict__ dots) {
  __shared__ __align__(16) unsigned char smem[49152];
  unsigned char* const XB = smem;
  unsigned char* const KT = smem;
  unsigned char* const VT = smem + 8192;
  unsigned char* const WB = smem + 16384;

  const int t = threadIdx.x;
  const int bx = blockIdx.x;
  const int h = bx >> 7;
  const int p = bx & 127;
  const int b = p >> 5;
  const int chunk = p & 31;
  const int row0 = chunk * 256;

  const int wave = t >> 6;
  const int lane = t & 63;
  const int lb = lane & 15;
  const int kg = lane >> 4;
  const unsigned int lxor = (unsigned int)(lb & 7) << 4;

  {
    const int k = t >> 1;
    const int chalf = t & 1;
    const float* wp = wqkv + (size_t)k * 1536 + (chalf ? (1024 + h * 64) : (512 + h * 64));
    const float4* wp4 = (const float4*)wp;
    const int c0 = chalf * 64;
    float4 wv[16];
    float sum = 0.f;
#pragma unroll
    for (int jj = 0; jj < 16; ++jj) {
      wv[jj] = wp4[jj];
      sum += wv[jj].x + wv[jj].y + wv[jj].z + wv[jj].w;
    }
    const float mean = sum * (1.f / 64.f);
#pragma unroll
    for (int jj = 0; jj < 16; ++jj) {
      const int c = c0 + jj * 4;
      const unsigned int cx0 = (unsigned int)((c + 0) & 7) << 4;
      const unsigned int cx1 = (unsigned int)((c + 1) & 7) << 4;
      const unsigned int cx2 = (unsigned int)((c + 2) & 7) << 4;
      const unsigned int cx3 = (unsigned int)((c + 3) & 7) << 4;
      *(unsigned short*)(WB + (c + 0) * 256 + (((unsigned)(2 * k)) ^ cx0)) = f2bf(wv[jj].x - mean);
      *(unsigned short*)(WB + (c + 1) * 256 + (((unsigned)(2 * k)) ^ cx1)) = f2bf(wv[jj].y - mean);
      *(unsigned short*)(WB + (c + 2) * 256 + (((unsigned)(2 * k)) ^ cx2)) = f2bf(wv[jj].z - mean);
      *(unsigned short*)(WB + (c + 3) * 256 + (((unsigned)(2 * k)) ^ cx3)) = f2bf(wv[jj].w - mean);
    }
  }

  f32x4 dacc[4];
#pragma unroll
  for (int nt = 0; nt < 4; ++nt) dacc[nt] = (f32x4)0.f;

  __syncthreads();

  for (int tile = 0; tile < 4; ++tile) {
    const int rowbase = row0 + tile * 64;
    __syncthreads();
    {
      const int r = t >> 2;
      const int cb = (t & 3) * 32;
      const float4* gp4 = (const float4*)(x + (size_t)(b * NN + rowbase + r) * DIM + cb);
      const unsigned int rxor = (unsigned int)(r & 7) << 4;
#pragma unroll
      for (int jj = 0; jj < 4; ++jj) {
        const float4 v0 = gp4[2 * jj];
        const float4 v1 = gp4[2 * jj + 1];
        uint4 u;
        u.x = cvtpk(v0.x, v0.y);
        u.y = cvtpk(v0.z, v0.w);
        u.z = cvtpk(v1.x, v1.y);
        u.w = cvtpk(v1.z, v1.w);
        *(uint4*)(XB + r * 256 + (((unsigned)(2 * cb + 16 * jj)) ^ rxor)) = u;
      }
    }
    __syncthreads();

    f32x4 acc[8];
#pragma unroll
    for (int ct = 0; ct < 8; ++ct) acc[ct] = (f32x4)0.f;
    const int arow = wave * 16 + lb;
#pragma unroll
    for (int ks = 0; ks < 4; ++ks) {
      const unsigned int koff = (unsigned int)(ks * 64 + kg * 16);
      const short8 a = *(const short8*)(XB + arow * 256 + (koff ^ lxor));
#pragma unroll
      for (int ct = 0; ct < 8; ++ct) {
        const short8 bf = *(const short8*)(WB + (ct * 16 + lb) * 256 + (koff ^ lxor));
        acc[ct] = __builtin_amdgcn_mfma_f32_16x16x32_bf16(a, bf, acc[ct], 0, 0, 0);
      }
    }

    float kscale[4];
#pragma unroll
    for (int e = 0; e < 4; ++e) {
      float sk = acc[0][e] * acc[0][e] + acc[1][e] * acc[1][e] +
                 acc[2][e] * acc[2][e] + acc[3][e] * acc[3][e];
      float sv = acc[4][e] * acc[4][e] + acc[5][e] * acc[5][e] +
                 acc[6][e] * acc[6][e] + acc[7][e] * acc[7][e];
      sk += __shfl_xor(sk, 1); sv += __shfl_xor(sv, 1);
      sk += __shfl_xor(sk, 2); sv += __shfl_xor(sv, 2);
      sk += __shfl_xor(sk, 4); sv += __shfl_xor(sv, 4);
      sk += __shfl_xor(sk, 8); sv += __shfl_xor(sv, 8);
      kscale[e] = rsqrtf(sk * (1.f / 64.f) + 1e-5f) * rsqrtf(sv * (1.f / 64.f) + 1e-5f);
    }

    __syncthreads();
    {
      const unsigned int rb2 = (unsigned int)(32 * wave + kg * 8);
#pragma unroll
      for (int ct = 0; ct < 4; ++ct) {
        uint2 w;
        w.x = cvtpk(acc[ct][0] * kscale[0], acc[ct][1] * kscale[1]);
        w.y = cvtpk(acc[ct][2] * kscale[2], acc[ct][3] * kscale[3]);
        *(uint2*)(KT + (ct * 16 + lb) * 128 + (rb2 ^ lxor)) = w;
      }
#pragma unroll
      for (int ct = 4; ct < 8; ++ct) {
        uint2 w;
        w.x = cvtpk(acc[ct][0], acc[ct][1]);
        w.y = cvtpk(acc[ct][2], acc[ct][3]);
        *(uint2*)(VT + ((ct - 4) * 16 + lb) * 128 + (rb2 ^ lxor)) = w;
      }
    }
    __syncthreads();

#pragma unroll
    for (int ks2 = 0; ks2 < 2; ++ks2) {
      const unsigned int koff = (unsigned int)(ks2 * 64 + kg * 16);
      const short8 a = *(const short8*)(KT + (wave * 16 + lb) * 128 + (koff ^ lxor));
#pragma unroll
      for (int nt = 0; nt < 4; ++nt) {
        const short8 bf = *(const short8*)(VT + (nt * 16 + lb) * 128 + (koff ^ lxor));
        dacc[nt] = __builtin_amdgcn_mfma_f32_16x16x32_bf16(a, bf, dacc[nt], 0, 0, 0);
      }
    }
  }

  float* dp = dots + (size_t)(b * 8 + h) * 4096;
#pragma unroll
  for (int nt = 0; nt < 4; ++nt) {
#pragma unroll
    for (int reg = 0; reg < 4; ++reg) {
      const int d = 16 * wave + kg * 4 + reg;
      const int e = nt * 16 + lb;
      atomicAdd(&dp[d * 64 + e], dacc[nt][reg]);
    }
  }
}

__global__ __launch_bounds__(256) void bigw_reduce_fb(const float* __restrict__ part,
                                                      float* __restrict__ bigw) {
  const int i = blockIdx.x * 256 + threadIdx.x;
  const int b = i >> 14;
  const int cj = i & 16383;
  const float* pp = part + (size_t)b * 8 * 16384 + cj;
  float s = 0.f;
#pragma unroll
  for (int h = 0; h < 8; ++h) s += pp[h * 16384];
  bigw[i] = s * (1.f / (float)NN);
}

__global__ __launch_bounds__(256) void out_fb(const float* __restrict__ x,
                                              const float* __restrict__ bigw,
                                              const float* __restrict__ bout,
                                              float* __restrict__ out) {
  __shared__ __align__(16) unsigned char smem[49152];
  unsigned char* const XB = smem;
  unsigned char* const WB = smem + 16384;

  const int t = threadIdx.x;
  const int bx = blockIdx.x;
  const int b = bx >> 7;
  const int rowbase = (bx & 127) * 64;

  const int wave = t >> 6;
  const int lane = t & 63;
  const int lb = lane & 15;
  const int kg = lane >> 4;
  const unsigned int lxor = (unsigned int)(lb & 7) << 4;

  {
    const int c = t >> 1;
    const int jhalf = t & 1;
    const float4* wp4 = (const float4*)(bigw + (size_t)b * 16384 + (size_t)c * 128 + jhalf * 64);
    const int j0 = jhalf * 64;
#pragma unroll
    for (int q = 0; q < 16; ++q) {
      const float4 v = wp4[q];
      const int j = j0 + q * 4;
      const unsigned int jx0 = (unsigned int)((j + 0) & 7) << 4;
      const unsigned int jx1 = (unsigned int)((j + 1) & 7) << 4;
      const unsigned int jx2 = (unsigned int)((j + 2) & 7) << 4;
      const unsigned int jx3 = (unsigned int)((j + 3) & 7) << 4;
      *(unsigned short*)(WB + (j + 0) * 256 + (((unsigned)(2 * c)) ^ jx0)) = f2bf(v.x);
      *(unsigned short*)(WB + (j + 1) * 256 + (((unsigned)(2 * c)) ^ jx1)) = f2bf(v.y);
      *(unsigned short*)(WB + (j + 2) * 256 + (((unsigned)(2 * c)) ^ jx2)) = f2bf(v.z);
      *(unsigned short*)(WB + (j + 3) * 256 + (((unsigned)(2 * c)) ^ jx3)) = f2bf(v.w);
    }
  }

  float bias[8];
#pragma unroll
  for (int ct = 0; ct < 8; ++ct) bias[ct] = bout[ct * 16 + lb];

  {
    const int r = t >> 2;
    const int cb = (t & 3) * 32;
    const float4* gp4 = (const float4*)(x + (size_t)(b * NN + rowbase + r) * DIM + cb);
    const unsigned int rxor = (unsigned int)(r & 7) << 4;
#pragma unroll
    for (int jj = 0; jj < 4; ++jj) {
      const float4 v0 = gp4[2 * jj];
      const float4 v1 = gp4[2 * jj + 1];
      uint4 u;
      u.x = cvtpk(v0.x, v0.y);
      u.y = cvtpk(v0.z, v0.w);
      u.z = cvtpk(v1.x, v1.y);
      u.w = cvtpk(v1.z, v1.w);
      *(uint4*)(XB + r * 256 + (((unsigned)(2 * cb + 16 * jj)) ^ rxor)) = u;
    }
  }
  __syncthreads();

  f32x4 acc[8];
#pragma unroll
  for (int ct = 0; ct < 8; ++ct) acc[ct] = (f32x4)0.f;
  const int arow = wave * 16 + lb;
#pragma unroll
  for (int ks = 0; ks < 4; ++ks) {
    const unsigned int koff = (unsigned int)(ks * 64 + kg * 16);
    const short8 a = *(const short8*)(XB + arow * 256 + (koff ^ lxor));
#pragma unroll
    for (int ct = 0; ct < 8; ++ct) {
      const short8 bf = *(const short8*)(WB + (ct * 16 + lb) * 256 + (koff ^ lxor));
      acc[ct] = __builtin_amdgcn_mfma_f32_16x16x32_bf16(a, bf, acc[ct], 0, 0, 0);
    }
  }

  float* op = out + (size_t)(b * NN + rowbase + 16 * wave + kg * 4) * DIM;
#pragma unroll
  for (int ct = 0; ct < 8; ++ct) {
#pragma unroll
    for (int reg = 0; reg < 4; ++reg) {
      op[reg * DIM + ct * 16 + lb] = acc[ct][reg] + bias[ct];
    }
  }
}

extern "C" void kernel_launch(void* const* d_in, const int* in_sizes, int n_in,
                              void* d_out, int out_size, void* d_ws, size_t ws_size,
                              hipStream_t stream) {
  (void)in_sizes; (void)n_in; (void)out_size;
  const float* x = (const float*)d_in[0];
  const float* wqkv = (const float*)d_in[1];
  const float* wout = (const float*)d_in[2];
  const float* bout = (const float*)d_in[3];
  float* out = (float*)d_out;

  const size_t NEED = 8388608ull + 262144ull + 131072ull + 524288ull + 2097152ull;
  if (ws_size >= NEED) {
    unsigned char* ximg = (unsigned char*)d_ws;            // 8 MB
    unsigned char* wimg = ximg + 8388608;                  // 256 KB
    unsigned char* bigwimg = wimg + 262144;                // 128 KB
    float* dots = (float*)(bigwimg + 131072);              // 512 KB
    float* part = dots + 131072;                           // 2 MB

    hipLaunchKernelGGL(prep_kernel, dim3(1040), dim3(256), 0, stream, x, wqkv, ximg, wimg, dots);
    hipLaunchKernelGGL(kv_dots_v2, dim3(1024), dim3(256), 0, stream, ximg, wimg, dots);
    hipLaunchKernelGGL((tw_kernel<1>), dim3(128), dim3(256), 0, stream, wqkv, wout, dots, part);
    hipLaunchKernelGGL(bigw_reduce_v2, dim3(32), dim3(256), 0, stream, part, bigwimg);
    hipLaunchKernelGGL(out_v2, dim3(512), dim3(256), 0, stream, ximg, bigwimg, bout, out);
  } else {
    float* dots = (float*)d_ws;
    float* part = dots + 131072;
    float* bigw = part + 524288;
    hipLaunchKernelGGL(zero_dots_fb, dim3(8), dim3(256), 0, stream, dots);
    hipLaunchKernelGGL(kv_dots_fb, dim3(1024), dim3(256), 0, stream, x, wqkv, dots);
    hipLaunchKernelGGL((tw_kernel<0>), dim3(128), dim3(256), 0, stream, wqkv, wout, dots, part);
    hipLaunchKernelGGL(bigw_reduce_fb, dim3(256), dim3(256), 0, stream, part, bigw);
    hipLaunchKernelGGL(out_fb, dim3(512), dim3(256), 0, stream, x, bigw, bout, out);
  }
}